// Round 17
// baseline (2190.434 us; speedup 1.0000x reference)
//
#include <hip/hip_runtime.h>
#include <hip/hip_bf16.h>
#include <cstdint>
#include <cstddef>

typedef _Float16 h16x8 __attribute__((ext_vector_type(8)));
typedef float f32x4 __attribute__((ext_vector_type(4)));

#define NSTRIPE 2

__device__ __forceinline__ void splitf16(float v, _Float16& hi, _Float16& lo) {
    hi = (_Float16)v;
    lo = (_Float16)(v - (float)hi);
}
__device__ __forceinline__ float swish_fast(float x) {
    float e = __expf(-x);
    return x * __builtin_amdgcn_rcpf(1.0f + e);
}

// ---------------- init: h = emb[atomic[z]] ----------------
__global__ void init_nodes(const int* __restrict__ z, const float* __restrict__ emb,
                           float* __restrict__ hf, _Float16* __restrict__ hhi, int N) {
    int tid = blockIdx.x * 256 + threadIdx.x;
    int n = tid >> 7, f = tid & 127;
    int zv = z[n];
    int idx5 = (zv == 1) ? 0 : (zv - 5);
    float v = emb[idx5 * 128 + f];
    hf[tid] = v;
    hhi[tid] = (_Float16)v;
}

// ---------------- edge preprocessing: counting sort by (dst_stripe, src) ----------------
__device__ __forceinline__ int edge_key(int d, int s, int N, int stripeSz) {
    return (d / stripeSz) * N + s;
}

__global__ void hist_kernel(const int* __restrict__ src, const int* __restrict__ dst,
                            int* __restrict__ hist, int E, int N, int stripeSz) {
    int e = blockIdx.x * 256 + threadIdx.x;
    if (e < E) atomicAdd(&hist[edge_key(dst[e], src[e], N, stripeSz)], 1);
}

__global__ void scan_p1(const int* __restrict__ hist, int* __restrict__ blocksum, int KN) {
    __shared__ int s[256];
    int idx = blockIdx.x * 256 + threadIdx.x;
    int v = (idx < KN) ? hist[idx] : 0;
    s[threadIdx.x] = v;
    __syncthreads();
    for (int d = 128; d > 0; d >>= 1) {
        if (threadIdx.x < d) s[threadIdx.x] += s[threadIdx.x + d];
        __syncthreads();
    }
    if (threadIdx.x == 0) blocksum[blockIdx.x] = s[0];
}

__global__ void scan_p2(int* __restrict__ blocksum, int NB) {
    __shared__ int s[1024];
    int t = threadIdx.x;
    int v = (t < NB) ? blocksum[t] : 0;
    s[t] = v;
    __syncthreads();
    for (int d = 1; d < 1024; d <<= 1) {
        int x = (t >= d) ? s[t - d] : 0;
        __syncthreads();
        s[t] += x;
        __syncthreads();
    }
    if (t < NB) blocksum[t] = s[t] - v;  // exclusive
}

__global__ void scan_p3(const int* __restrict__ hist, const int* __restrict__ blocksum,
                        int* __restrict__ cursor, int KN) {
    __shared__ int s[256];
    int idx = blockIdx.x * 256 + threadIdx.x;
    int v = (idx < KN) ? hist[idx] : 0;
    s[threadIdx.x] = v;
    __syncthreads();
    for (int d = 1; d < 256; d <<= 1) {
        int x = (threadIdx.x >= d) ? s[threadIdx.x - d] : 0;
        __syncthreads();
        s[threadIdx.x] += x;
        __syncthreads();
    }
    if (idx < KN) cursor[idx] = blocksum[blockIdx.x] + s[threadIdx.x] - v;
}

__global__ void scatter_kernel(const int* __restrict__ src, const int* __restrict__ dst,
                               int* __restrict__ cursor, int* __restrict__ perm,
                               int E, int N, int stripeSz) {
    int e = blockIdx.x * 256 + threadIdx.x;
    if (e < E) {
        int p = atomicAdd(&cursor[edge_key(dst[e], src[e], N, stripeSz)], 1);
        perm[p] = e;
    }
}

__global__ void reorder_kernel(const int* __restrict__ perm, const int* __restrict__ src,
                               const int* __restrict__ dst, const float* __restrict__ pos,
                               int* __restrict__ srcS, int* __restrict__ dstS,
                               float* __restrict__ n2S, int E) {
    int i = blockIdx.x * 256 + threadIdx.x;
    if (i >= E) return;
    int e = perm[i];
    int si = src[e], di = dst[e];
    srcS[i] = si;
    dstS[i] = di;
    float dx = pos[si * 3 + 0] - pos[di * 3 + 0];
    float dy = pos[si * 3 + 1] - pos[di * 3 + 1];
    float dz = pos[si * 3 + 2] - pos[di * 3 + 2];
    n2S[i] = dx * dx + dy * dy + dz * dz;
}

// ---------------- batched pack W_msg1 + W_msg2 (all 7 layers) ----------------
__global__ void pack_msg1(const float* __restrict__ Wm1, const float* __restrict__ bm1,
                          const float* __restrict__ Wm2,
                          _Float16* __restrict__ Bp1A, float* __restrict__ biasA,
                          _Float16* __restrict__ w1cA, _Float16* __restrict__ W2pA) {
    int l = blockIdx.y;
    const float* Wm1l = Wm1 + (size_t)l * 257 * 514;
    const float* bm1l = bm1 + (size_t)l * 514;
    const float* Wm2l = Wm2 + (size_t)l * 514 * 16;
    _Float16* Bp1 = Bp1A + (size_t)l * 139264;
    float* bias1088 = biasA + (size_t)l * 1088;
    _Float16* w1c = w1cA + (size_t)l * 544;
    _Float16* W2p = W2pA + (size_t)l * 8704;

    int t = blockIdx.x * 256 + threadIdx.x;
    int i = t & 7;
    int lane = (t >> 3) & 63;
    int rest = t >> 9;
    int cb = rest % 68;
    int ks = rest / 68;
    int k = ks * 32 + ((lane >> 4) << 3) + i;
    int ch = cb * 16 + (lane & 15);
    float val;
    if (ch < 544) {
        val = (ch < 514) ? Wm1l[k * 514 + ch] : 0.f;
    } else {
        int c = ch - 544;
        val = (c < 514) ? Wm1l[(128 + k) * 514 + c] : 0.f;
    }
    Bp1[t] = (_Float16)val;
    if (t < 1088) bias1088[t] = (t < 514) ? bm1l[t] : 0.f;
    if (t < 544) w1c[t] = (_Float16)((t < 514) ? Wm1l[256 * 514 + t] : 0.f);
    if (t < 8704) {
        int i2 = t & 7, lane2 = (t >> 3) & 63, ks2 = t >> 9;
        int k2 = ks2 * 32 + ((lane2 >> 4) << 3) + i2;
        int c2 = lane2 & 15;
        W2p[t] = (_Float16)((k2 < 514) ? Wm2l[k2 * 16 + c2] : 0.f);
    }
}

// ---------------- batched generic B packer ----------------
__global__ void pack_generic(const float* __restrict__ Wall, size_t strideW, int K, int Nc,
                             _Float16* __restrict__ BpAll, size_t strideB) {
    int l = blockIdx.y;
    const float* W = Wall + (size_t)l * strideW;
    _Float16* Bp = BpAll + (size_t)l * strideB;
    int t = blockIdx.x * 256 + threadIdx.x;
    int i = t & 7;
    int lane = (t >> 3) & 63;
    int rest = t >> 9;
    int CB = Nc >> 4;
    int cb = rest % CB;
    int ks = rest / CB;
    int k = ks * 32 + ((lane >> 4) << 3) + i;
    int c = cb * 16 + (lane & 15);
    float val = (k < K) ? W[(size_t)k * Nc + c] : 0.f;
    Bp[t] = (_Float16)val;
}

// ---------------- standalone table GEMM (layer 0): A hi-only + agg zeroing ----------------
__global__ __launch_bounds__(256) void tab_gemm(
    const _Float16* __restrict__ Ahi,
    const _Float16* __restrict__ Bp, const float* __restrict__ bias,
    _Float16* __restrict__ TA, _Float16* __restrict__ TB, float* __restrict__ agg, int N) {
    {
        int base = blockIdx.x * 1024 + threadIdx.x;
#pragma unroll
        for (int q = 0; q < 4; ++q) {
            int idx = base + q * 256;
            if (idx < N * 16) agg[idx] = 0.f;
        }
    }
    int lane = threadIdx.x & 63;
    int wid = threadIdx.x >> 6;
    int row0 = blockIdx.x * 64 + wid * 16;
    if (row0 >= N) return;
    const size_t arow = (size_t)(row0 + (lane & 15)) * 128;
    const int ak = (lane >> 4) * 8;
    h16x8 ah[4];
#pragma unroll
    for (int ks = 0; ks < 4; ++ks)
        ah[ks] = *(const h16x8*)(Ahi + arow + ks * 32 + ak);
    int col16 = lane & 15;
    int rb = (lane >> 4) * 4;
    for (int cb = 0; cb < 68; ++cb) {
        f32x4 acc = {0.f, 0.f, 0.f, 0.f};
#pragma unroll
        for (int ks = 0; ks < 4; ++ks) {
            h16x8 bh = *(const h16x8*)(Bp + ((size_t)(ks * 68 + cb) * 64 + lane) * 8);
            acc = __builtin_amdgcn_mfma_f32_16x16x32_f16(ah[ks], bh, acc, 0, 0, 0);
        }
        int col = cb * 16 + col16;
        float bv = bias[col];
        if (cb < 34) {
#pragma unroll
            for (int i = 0; i < 4; ++i)
                TA[(size_t)(row0 + rb + i) * 544 + col] = (_Float16)(acc[i] + bv);
        } else {
#pragma unroll
            for (int i = 0; i < 4; ++i)
                TB[(size_t)(row0 + rb + i) * 544 + (col - 544)] = (_Float16)(acc[i] + bv);
        }
    }
}

// ---------------- fused node kernel ----------------
// phase1: up1 (x=[agg|h|0] @ Wu1, swish) -> u in LDS (hi/lo)
// phase2: up2 (u @ Wu2) + resid -> h; hf updated; h kept in LDS
// MODE 0: phase3 = next layer's table GEMM from LDS h (hi-only) + agg re-zero
// MODE 1: phase3 = proj1 (swish) -> t1 LDS (hi/lo); phase4 = proj2 + pooled atomic
template <int MODE>
__global__ __launch_bounds__(256) void up_combo(
    const float* __restrict__ agg, float* __restrict__ hf,
    const _Float16* __restrict__ Bp1, const float* __restrict__ b1,
    const _Float16* __restrict__ Bp2, const float* __restrict__ b2,
    const _Float16* __restrict__ BpX1, const float* __restrict__ bX1,
    const _Float16* __restrict__ BpX2, const float* __restrict__ bX2,
    _Float16* __restrict__ TA, _Float16* __restrict__ TB, float* __restrict__ aggz,
    const int* __restrict__ batch, float* __restrict__ pooled, int N) {
    __shared__ _Float16 sA[4][16][272];
    __shared__ _Float16 sB[4][16][272];
    int lane = threadIdx.x & 63;
    int wid = threadIdx.x >> 6;
    int row0 = blockIdx.x * 64 + wid * 16;
    int col16 = lane & 15;
    int rb = (lane >> 4) * 4;
    const int ak = (lane >> 4) * 8;

    if (row0 < N) {
        int r = row0 + col16;
        // ---- phase 1: up1 ----
        h16x8 ah[5], al[5];
#pragma unroll
        for (int ks = 0; ks < 5; ++ks) {
            int c0 = ks * 32 + ak;
            f32x4 v0, v1;
            if (c0 < 16) {
                v0 = *(const f32x4*)(agg + (size_t)r * 16 + c0);
                v1 = *(const f32x4*)(agg + (size_t)r * 16 + c0 + 4);
            } else if (c0 < 144) {
                v0 = *(const f32x4*)(hf + (size_t)r * 128 + c0 - 16);
                v1 = *(const f32x4*)(hf + (size_t)r * 128 + c0 - 12);
            } else {
                v0 = f32x4{0.f, 0.f, 0.f, 0.f};
                v1 = f32x4{0.f, 0.f, 0.f, 0.f};
            }
            h16x8 hi8, lo8;
#pragma unroll
            for (int jj = 0; jj < 8; ++jj) {
                float x = (jj < 4) ? v0[jj] : v1[jj - 4];
                _Float16 h, l;
                splitf16(x, h, l);
                hi8[jj] = h;
                lo8[jj] = l;
            }
            ah[ks] = hi8;
            al[ks] = lo8;
        }
        for (int cb = 0; cb < 16; ++cb) {
            f32x4 acc = {0.f, 0.f, 0.f, 0.f};
#pragma unroll
            for (int ks = 0; ks < 5; ++ks) {
                h16x8 bh = *(const h16x8*)(Bp1 + ((size_t)(ks * 16 + cb) * 64 + lane) * 8);
                acc = __builtin_amdgcn_mfma_f32_16x16x32_f16(ah[ks], bh, acc, 0, 0, 0);
                acc = __builtin_amdgcn_mfma_f32_16x16x32_f16(al[ks], bh, acc, 0, 0, 0);
            }
            int col = cb * 16 + col16;
            float bv = b1[col];
#pragma unroll
            for (int i = 0; i < 4; ++i) {
                float s = swish_fast(acc[i] + bv);
                _Float16 hi, lo;
                splitf16(s, hi, lo);
                sA[wid][rb + i][col] = hi;
                sB[wid][rb + i][col] = lo;
            }
        }
    }
    __syncthreads();
    // after all of this block's phase-1 agg reads: re-zero own agg rows (MODE 0)
    if (MODE == 0) {
        int base = blockIdx.x * 1024 + threadIdx.x;
#pragma unroll
        for (int q = 0; q < 4; ++q) {
            int idx = base + q * 256;
            if (idx < N * 16) aggz[idx] = 0.f;
        }
    }
    if (row0 >= N) return;
    // ---- phase 2: up2 + resid -> h ----
    h16x8 ah2[8], al2[8];
#pragma unroll
    for (int ks = 0; ks < 8; ++ks) {
        ah2[ks] = *(const h16x8*)(&sA[wid][col16][ks * 32 + ak]);
        al2[ks] = *(const h16x8*)(&sB[wid][col16][ks * 32 + ak]);
    }
    __syncthreads();
    for (int cb = 0; cb < 8; ++cb) {
        f32x4 acc = {0.f, 0.f, 0.f, 0.f};
#pragma unroll
        for (int ks = 0; ks < 8; ++ks) {
            h16x8 bh = *(const h16x8*)(Bp2 + ((size_t)(ks * 8 + cb) * 64 + lane) * 8);
            acc = __builtin_amdgcn_mfma_f32_16x16x32_f16(ah2[ks], bh, acc, 0, 0, 0);
            acc = __builtin_amdgcn_mfma_f32_16x16x32_f16(al2[ks], bh, acc, 0, 0, 0);
        }
        int col = cb * 16 + col16;
        float bv = b2[col];
#pragma unroll
        for (int i = 0; i < 4; ++i) {
            int row = row0 + rb + i;
            float h = acc[i] + bv + hf[(size_t)row * 128 + col];
            if (MODE == 0) hf[(size_t)row * 128 + col] = h;
            _Float16 hi, lo;
            splitf16(h, hi, lo);
            sA[wid][rb + i][col] = hi;
            if (MODE == 1) sB[wid][rb + i][col] = lo;
        }
    }
    __syncthreads();
    if (MODE == 0) {
        // ---- phase 3: next layer's table GEMM (hi-only A from LDS) ----
        h16x8 ah3[4];
#pragma unroll
        for (int ks = 0; ks < 4; ++ks)
            ah3[ks] = *(const h16x8*)(&sA[wid][col16][ks * 32 + ak]);
        for (int cb = 0; cb < 68; ++cb) {
            f32x4 acc = {0.f, 0.f, 0.f, 0.f};
#pragma unroll
            for (int ks = 0; ks < 4; ++ks) {
                h16x8 bh = *(const h16x8*)(BpX1 + ((size_t)(ks * 68 + cb) * 64 + lane) * 8);
                acc = __builtin_amdgcn_mfma_f32_16x16x32_f16(ah3[ks], bh, acc, 0, 0, 0);
            }
            int col = cb * 16 + col16;
            float bv = bX1[col];
            if (cb < 34) {
#pragma unroll
                for (int i = 0; i < 4; ++i)
                    TA[(size_t)(row0 + rb + i) * 544 + col] = (_Float16)(acc[i] + bv);
            } else {
#pragma unroll
                for (int i = 0; i < 4; ++i)
                    TB[(size_t)(row0 + rb + i) * 544 + (col - 544)] = (_Float16)(acc[i] + bv);
            }
        }
    } else {
        // ---- phase 3: proj1 -> t1 in LDS ----
        h16x8 ah3[4], al3[4];
#pragma unroll
        for (int ks = 0; ks < 4; ++ks) {
            ah3[ks] = *(const h16x8*)(&sA[wid][col16][ks * 32 + ak]);
            al3[ks] = *(const h16x8*)(&sB[wid][col16][ks * 32 + ak]);
        }
        __syncthreads();
        for (int cb = 0; cb < 8; ++cb) {
            f32x4 acc = {0.f, 0.f, 0.f, 0.f};
#pragma unroll
            for (int ks = 0; ks < 4; ++ks) {
                h16x8 bh = *(const h16x8*)(BpX1 + ((size_t)(ks * 8 + cb) * 64 + lane) * 8);
                acc = __builtin_amdgcn_mfma_f32_16x16x32_f16(ah3[ks], bh, acc, 0, 0, 0);
                acc = __builtin_amdgcn_mfma_f32_16x16x32_f16(al3[ks], bh, acc, 0, 0, 0);
            }
            int col = cb * 16 + col16;
            float bv = bX1[col];
#pragma unroll
            for (int i = 0; i < 4; ++i) {
                float s = swish_fast(acc[i] + bv);
                _Float16 hi, lo;
                splitf16(s, hi, lo);
                sA[wid][rb + i][col] = hi;
                sB[wid][rb + i][col] = lo;
            }
        }
        __syncthreads();
        // ---- phase 4: proj2 + pooled atomic ----
        h16x8 ah4[4], al4[4];
#pragma unroll
        for (int ks = 0; ks < 4; ++ks) {
            ah4[ks] = *(const h16x8*)(&sA[wid][col16][ks * 32 + ak]);
            al4[ks] = *(const h16x8*)(&sB[wid][col16][ks * 32 + ak]);
        }
        for (int cb = 0; cb < 8; ++cb) {
            f32x4 acc = {0.f, 0.f, 0.f, 0.f};
#pragma unroll
            for (int ks = 0; ks < 4; ++ks) {
                h16x8 bh = *(const h16x8*)(BpX2 + ((size_t)(ks * 8 + cb) * 64 + lane) * 8);
                acc = __builtin_amdgcn_mfma_f32_16x16x32_f16(ah4[ks], bh, acc, 0, 0, 0);
                acc = __builtin_amdgcn_mfma_f32_16x16x32_f16(al4[ks], bh, acc, 0, 0, 0);
            }
            int col = cb * 16 + col16;
            float bv = bX2[col];
#pragma unroll
            for (int i = 0; i < 4; ++i) {
                int row = row0 + rb + i;
                unsafeAtomicAdd(&pooled[(size_t)batch[row] * 128 + col], acc[i] + bv);
            }
        }
    }
}

// ---------------- edge kernel ----------------
__global__ __launch_bounds__(256) void edge_kernel(
    const _Float16* __restrict__ TA, const _Float16* __restrict__ TB,
    const _Float16* __restrict__ w1c, const _Float16* __restrict__ W2p,
    const float* __restrict__ bm2l,
    const int* __restrict__ srcS, const int* __restrict__ dstS,
    const float* __restrict__ n2S, float* __restrict__ agg) {
    __shared__ _Float16 sW[8704];
    __shared__ _Float16 sw1[544];
    for (int t = threadIdx.x; t < 1088; t += 256)
        ((h16x8*)sW)[t] = ((const h16x8*)W2p)[t];
    for (int t = threadIdx.x; t < 544; t += 256) sw1[t] = w1c[t];
    __syncthreads();

    int lane = threadIdx.x & 63;
    int wid = threadIdx.x >> 6;
    int ebase = blockIdx.x * 128 + wid * 32;
    int rr = lane & 15;
    int e0 = ebase + rr;
    int e1 = ebase + 16 + rr;
    int di0 = dstS[e0], si0 = srcS[e0];
    int di1 = dstS[e1], si1 = srcS[e1];
    _Float16 n20 = (_Float16)n2S[e0];
    _Float16 n21 = (_Float16)n2S[e1];
    const int ak = (lane >> 4) * 8;
    const _Float16* pa0 = TA + (size_t)di0 * 544 + ak;
    const _Float16* pb0 = TB + (size_t)si0 * 544 + ak;
    const _Float16* pa1 = TA + (size_t)di1 * 544 + ak;
    const _Float16* pb1 = TB + (size_t)si1 * 544 + ak;

    const _Float16 nl2e = (_Float16)(-1.44269504f);
    f32x4 acc0 = {0.f, 0.f, 0.f, 0.f};
    f32x4 acc1 = {0.f, 0.f, 0.f, 0.f};

    h16x8 bufA[16], bufB[16], bufT[4];

    auto issue4 = [&](h16x8* buf, int K) {
#pragma unroll
        for (int q = 0; q < 4; ++q) {
            buf[q * 4 + 0] = *(const h16x8*)(pa0 + (K + q) * 32);
            buf[q * 4 + 1] = *(const h16x8*)(pb0 + (K + q) * 32);
            buf[q * 4 + 2] = *(const h16x8*)(pa1 + (K + q) * 32);
            buf[q * 4 + 3] = *(const h16x8*)(pb1 + (K + q) * 32);
        }
    };
    auto step = [&](const h16x8* buf, int q, int ks) {
        h16x8 va0 = buf[q * 4 + 0], vb0 = buf[q * 4 + 1];
        h16x8 va1 = buf[q * 4 + 2], vb1 = buf[q * 4 + 3];
        h16x8 wv = *(const h16x8*)(sw1 + ks * 32 + ak);
        h16x8 x0 = va0 + vb0 + wv * n20;
        h16x8 ev0 = __builtin_elementwise_exp2(x0 * nl2e);
        h16x8 d0 = ev0 + (_Float16)1.0f;
        h16x8 r0;
#pragma unroll
        for (int j = 0; j < 8; ++j) r0[j] = __builtin_amdgcn_rcph(d0[j]);
        h16x8 m0 = x0 * r0;
        h16x8 x1 = va1 + vb1 + wv * n21;
        h16x8 ev1 = __builtin_elementwise_exp2(x1 * nl2e);
        h16x8 d1 = ev1 + (_Float16)1.0f;
        h16x8 r1;
#pragma unroll
        for (int j = 0; j < 8; ++j) r1[j] = __builtin_amdgcn_rcph(d1[j]);
        h16x8 m1 = x1 * r1;
        h16x8 bh = *(const h16x8*)(sW + (ks * 64 + lane) * 8);
        acc0 = __builtin_amdgcn_mfma_f32_16x16x32_f16(m0, bh, acc0, 0, 0, 0);
        acc1 = __builtin_amdgcn_mfma_f32_16x16x32_f16(m1, bh, acc1, 0, 0, 0);
    };

    issue4(bufA, 0);
    __builtin_amdgcn_sched_barrier(0);
    issue4(bufB, 4);
    __builtin_amdgcn_sched_barrier(0);
#pragma unroll
    for (int q = 0; q < 4; ++q) step(bufA, q, q);
    issue4(bufA, 8);
    __builtin_amdgcn_sched_barrier(0);
#pragma unroll
    for (int q = 0; q < 4; ++q) step(bufB, q, 4 + q);
    issue4(bufB, 12);
    __builtin_amdgcn_sched_barrier(0);
#pragma unroll
    for (int q = 0; q < 4; ++q) step(bufA, q, 8 + q);
    bufT[0] = *(const h16x8*)(pa0 + 16 * 32);
    bufT[1] = *(const h16x8*)(pb0 + 16 * 32);
    bufT[2] = *(const h16x8*)(pa1 + 16 * 32);
    bufT[3] = *(const h16x8*)(pb1 + 16 * 32);
    __builtin_amdgcn_sched_barrier(0);
#pragma unroll
    for (int q = 0; q < 4; ++q) step(bufB, q, 12 + q);
    step(bufT, 0, 16);

    int col = lane & 15;
    float b2 = bm2l[col];
#pragma unroll
    for (int i = 0; i < 4; ++i) {
        int ea = ebase + (lane >> 4) * 4 + i;
        float v0 = swish_fast(acc0[i] + b2);
        unsafeAtomicAdd(&agg[(size_t)dstS[ea] * 16 + col], v0);
        int eb = ea + 16;
        float v1 = swish_fast(acc1[i] + b2);
        unsafeAtomicAdd(&agg[(size_t)dstS[eb] * 16 + col], v1);
    }
}

// ---------------- readout ----------------
__global__ void readout(const float* __restrict__ pooled, const float* __restrict__ Wr1,
                        const float* __restrict__ br1, const float* __restrict__ Wr2,
                        const float* __restrict__ br2, float* __restrict__ out) {
    __shared__ float row[128];
    __shared__ float tt[128];
    int g = blockIdx.x;
    int t = threadIdx.x;
    row[t] = pooled[g * 128 + t];
    __syncthreads();
    float s = br1[t];
    for (int k = 0; k < 128; ++k) s += row[k] * Wr1[k * 128 + t];
    tt[t] = swish_fast(s);
    __syncthreads();
    if (t < 12) {
        float o = br2[t];
        for (int j = 0; j < 128; ++j) o += tt[j] * Wr2[j * 12 + t];
        out[g * 12 + t] = o;
    }
}

extern "C" void kernel_launch(void* const* d_in, const int* in_sizes, int n_in,
                              void* d_out, int out_size, void* d_ws, size_t ws_size,
                              hipStream_t stream) {
    const float* pos = (const float*)d_in[0];
    const int* z = (const int*)d_in[1];
    const int* ei = (const int*)d_in[2];
    const int* batch = (const int*)d_in[3];
    const float* emb = (const float*)d_in[4];
    const float* Wm1 = (const float*)d_in[5];
    const float* bm1 = (const float*)d_in[6];
    const float* Wm2 = (const float*)d_in[7];
    const float* bm2 = (const float*)d_in[8];
    const float* Wu1 = (const float*)d_in[9];
    const float* bu1 = (const float*)d_in[10];
    const float* Wu2 = (const float*)d_in[11];
    const float* bu2 = (const float*)d_in[12];
    const float* Wp1 = (const float*)d_in[13];
    const float* bp1v = (const float*)d_in[14];
    const float* Wp2 = (const float*)d_in[15];
    const float* bp2v = (const float*)d_in[16];
    const float* Wr1 = (const float*)d_in[17];
    const float* br1 = (const float*)d_in[18];
    const float* Wr2 = (const float*)d_in[19];
    const float* br2 = (const float*)d_in[20];

    const int N = in_sizes[0] / 3;   // 50000
    const int E = in_sizes[2] / 2;   // 800000
    const int G = out_size / 12;     // 1000
    const int* src = ei;
    const int* dstp = ei + E;
    const int stripeSz = (N + NSTRIPE - 1) / NSTRIPE;
    const int KN = NSTRIPE * N;
    const int NB = (KN + 255) / 256;

    char* ws = (char*)d_ws;
    size_t off = 0;
    auto alloc = [&](size_t bytes) -> char* {
        char* p = ws + off;
        off += (bytes + 255) & ~(size_t)255;
        return p;
    };
    _Float16* TA = (_Float16*)alloc((size_t)N * 544 * 2);
    _Float16* TB = (_Float16*)alloc((size_t)N * 544 * 2);
    float* hf = (float*)alloc((size_t)N * 128 * 4);
    _Float16* hhi = (_Float16*)alloc((size_t)N * 128 * 2);
    float* agg = (float*)alloc((size_t)N * 16 * 4);
    float* pooled = (float*)alloc((size_t)G * 128 * 4);
    int* hist = (int*)alloc((size_t)KN * 4);
    int* cursor = (int*)alloc((size_t)KN * 4);
    int* blocksum = (int*)alloc((size_t)NB * 4);
    int* perm = (int*)alloc((size_t)E * 4);
    int* srcS = (int*)alloc((size_t)E * 4);
    int* dstS = (int*)alloc((size_t)E * 4);
    float* n2S = (float*)alloc((size_t)E * 4);
    _Float16* Bp1A = (_Float16*)alloc((size_t)7 * 139264 * 2);
    float* biasA = (float*)alloc((size_t)7 * 1088 * 4);
    _Float16* w1cA = (_Float16*)alloc((size_t)7 * 544 * 2);
    _Float16* W2pA = (_Float16*)alloc((size_t)7 * 8704 * 2);
    _Float16* BpU1A = (_Float16*)alloc((size_t)7 * 40960 * 2);
    _Float16* BpU2A = (_Float16*)alloc((size_t)7 * 32768 * 2);
    _Float16* BpP1 = (_Float16*)alloc(16384 * 2);
    _Float16* BpP2 = (_Float16*)alloc(16384 * 2);

    init_nodes<<<(N * 128) / 256, 256, 0, stream>>>(z, emb, hf, hhi, N);

    // one-time: counting sort of edges by (dst_stripe, src)
    hipMemsetAsync(hist, 0, (size_t)KN * 4, stream);
    hist_kernel<<<(E + 255) / 256, 256, 0, stream>>>(src, dstp, hist, E, N, stripeSz);
    scan_p1<<<NB, 256, 0, stream>>>(hist, blocksum, KN);
    scan_p2<<<1, 1024, 0, stream>>>(blocksum, NB);
    scan_p3<<<NB, 256, 0, stream>>>(hist, blocksum, cursor, KN);
    scatter_kernel<<<(E + 255) / 256, 256, 0, stream>>>(src, dstp, cursor, perm, E, N, stripeSz);
    reorder_kernel<<<(E + 255) / 256, 256, 0, stream>>>(perm, src, dstp, pos, srcS, dstS, n2S, E);

    // one-time: pack all layers' weights
    pack_msg1<<<dim3(139264 / 256, 7), 256, 0, stream>>>(Wm1, bm1, Wm2, Bp1A, biasA, w1cA, W2pA);
    pack_generic<<<dim3(160, 7), 256, 0, stream>>>(Wu1, (size_t)144 * 256, 144, 256, BpU1A, 40960);
    pack_generic<<<dim3(128, 7), 256, 0, stream>>>(Wu2, (size_t)256 * 128, 256, 128, BpU2A, 32768);
    pack_generic<<<dim3(64, 1), 256, 0, stream>>>(Wp1, 0, 128, 128, BpP1, 0);
    pack_generic<<<dim3(64, 1), 256, 0, stream>>>(Wp2, 0, 128, 128, BpP2, 0);
    hipMemsetAsync(pooled, 0, (size_t)G * 128 * 4, stream);

    const int gA = (N + 63) / 64;
    tab_gemm<<<gA, 256, 0, stream>>>(hhi, Bp1A, biasA, TA, TB, agg, N);
    for (int l = 0; l < 7; ++l) {
        edge_kernel<<<E / 128, 256, 0, stream>>>(TA, TB, w1cA + (size_t)l * 544,
                                                 W2pA + (size_t)l * 8704, bm2 + l * 16,
                                                 srcS, dstS, n2S, agg);
        if (l < 6) {
            up_combo<0><<<gA, 256, 0, stream>>>(
                agg, hf, BpU1A + (size_t)l * 40960, bu1 + l * 256,
                BpU2A + (size_t)l * 32768, bu2 + l * 128,
                Bp1A + (size_t)(l + 1) * 139264, biasA + (size_t)(l + 1) * 1088,
                nullptr, nullptr, TA, TB, agg, nullptr, nullptr, N);
        } else {
            up_combo<1><<<gA, 256, 0, stream>>>(
                agg, hf, BpU1A + (size_t)l * 40960, bu1 + l * 256,
                BpU2A + (size_t)l * 32768, bu2 + l * 128,
                BpP1, bp1v, BpP2, bp2v,
                nullptr, nullptr, nullptr, batch, pooled, N);
        }
    }
    readout<<<G, 128, 0, stream>>>(pooled, Wr1, br1, Wr2, br2, (float*)d_out);
}

// Round 18
// 1904.395 us; speedup vs baseline: 1.1502x; 1.1502x over previous
//
#include <hip/hip_runtime.h>
#include <hip/hip_bf16.h>
#include <cstdint>
#include <cstddef>

typedef _Float16 h16x8 __attribute__((ext_vector_type(8)));
typedef float f32x4 __attribute__((ext_vector_type(4)));

#define NSTRIPE 2

__device__ __forceinline__ void splitf16(float v, _Float16& hi, _Float16& lo) {
    hi = (_Float16)v;
    lo = (_Float16)(v - (float)hi);
}
__device__ __forceinline__ float swish_fast(float x) {
    float e = __expf(-x);
    return x * __builtin_amdgcn_rcpf(1.0f + e);
}

// ---------------- init: h = emb[atomic[z]] ----------------
__global__ void init_nodes(const int* __restrict__ z, const float* __restrict__ emb,
                           float* __restrict__ hf, _Float16* __restrict__ hhi, int N) {
    int tid = blockIdx.x * 256 + threadIdx.x;
    int n = tid >> 7, f = tid & 127;
    int zv = z[n];
    int idx5 = (zv == 1) ? 0 : (zv - 5);
    float v = emb[idx5 * 128 + f];
    hf[tid] = v;
    hhi[tid] = (_Float16)v;
}

// ---------------- edge preprocessing: counting sort by (dst_stripe, src) ----------------
__device__ __forceinline__ int edge_key(int d, int s, int N, int stripeSz) {
    return (d / stripeSz) * N + s;
}

__global__ void hist_kernel(const int* __restrict__ src, const int* __restrict__ dst,
                            int* __restrict__ hist, int E, int N, int stripeSz) {
    int e = blockIdx.x * 256 + threadIdx.x;
    if (e < E) atomicAdd(&hist[edge_key(dst[e], src[e], N, stripeSz)], 1);
}

__global__ void scan_p1(const int* __restrict__ hist, int* __restrict__ blocksum, int KN) {
    __shared__ int s[256];
    int idx = blockIdx.x * 256 + threadIdx.x;
    int v = (idx < KN) ? hist[idx] : 0;
    s[threadIdx.x] = v;
    __syncthreads();
    for (int d = 128; d > 0; d >>= 1) {
        if (threadIdx.x < d) s[threadIdx.x] += s[threadIdx.x + d];
        __syncthreads();
    }
    if (threadIdx.x == 0) blocksum[blockIdx.x] = s[0];
}

__global__ void scan_p2(int* __restrict__ blocksum, int NB) {
    __shared__ int s[1024];
    int t = threadIdx.x;
    int v = (t < NB) ? blocksum[t] : 0;
    s[t] = v;
    __syncthreads();
    for (int d = 1; d < 1024; d <<= 1) {
        int x = (t >= d) ? s[t - d] : 0;
        __syncthreads();
        s[t] += x;
        __syncthreads();
    }
    if (t < NB) blocksum[t] = s[t] - v;  // exclusive
}

__global__ void scan_p3(const int* __restrict__ hist, const int* __restrict__ blocksum,
                        int* __restrict__ cursor, int KN) {
    __shared__ int s[256];
    int idx = blockIdx.x * 256 + threadIdx.x;
    int v = (idx < KN) ? hist[idx] : 0;
    s[threadIdx.x] = v;
    __syncthreads();
    for (int d = 1; d < 256; d <<= 1) {
        int x = (threadIdx.x >= d) ? s[threadIdx.x - d] : 0;
        __syncthreads();
        s[threadIdx.x] += x;
        __syncthreads();
    }
    if (idx < KN) cursor[idx] = blocksum[blockIdx.x] + s[threadIdx.x] - v;
}

__global__ void scatter_kernel(const int* __restrict__ src, const int* __restrict__ dst,
                               int* __restrict__ cursor, int* __restrict__ perm,
                               int E, int N, int stripeSz) {
    int e = blockIdx.x * 256 + threadIdx.x;
    if (e < E) {
        int p = atomicAdd(&cursor[edge_key(dst[e], src[e], N, stripeSz)], 1);
        perm[p] = e;
    }
}

__global__ void reorder_kernel(const int* __restrict__ perm, const int* __restrict__ src,
                               const int* __restrict__ dst, const float* __restrict__ pos,
                               int* __restrict__ srcS, int* __restrict__ dstS,
                               float* __restrict__ n2S, int E) {
    int i = blockIdx.x * 256 + threadIdx.x;
    if (i >= E) return;
    int e = perm[i];
    int si = src[e], di = dst[e];
    srcS[i] = si;
    dstS[i] = di;
    float dx = pos[si * 3 + 0] - pos[di * 3 + 0];
    float dy = pos[si * 3 + 1] - pos[di * 3 + 1];
    float dz = pos[si * 3 + 2] - pos[di * 3 + 2];
    n2S[i] = dx * dx + dy * dy + dz * dz;
}

// ---------------- batched pack W_msg1 + W_msg2 (all 7 layers) ----------------
__global__ void pack_msg1(const float* __restrict__ Wm1, const float* __restrict__ bm1,
                          const float* __restrict__ Wm2,
                          _Float16* __restrict__ Bp1A, float* __restrict__ biasA,
                          _Float16* __restrict__ w1cA, _Float16* __restrict__ W2pA) {
    int l = blockIdx.y;
    const float* Wm1l = Wm1 + (size_t)l * 257 * 514;
    const float* bm1l = bm1 + (size_t)l * 514;
    const float* Wm2l = Wm2 + (size_t)l * 514 * 16;
    _Float16* Bp1 = Bp1A + (size_t)l * 139264;
    float* bias1088 = biasA + (size_t)l * 1088;
    _Float16* w1c = w1cA + (size_t)l * 544;
    _Float16* W2p = W2pA + (size_t)l * 8704;

    int t = blockIdx.x * 256 + threadIdx.x;
    int i = t & 7;
    int lane = (t >> 3) & 63;
    int rest = t >> 9;
    int cb = rest % 68;
    int ks = rest / 68;
    int k = ks * 32 + ((lane >> 4) << 3) + i;
    int ch = cb * 16 + (lane & 15);
    float val;
    if (ch < 544) {
        val = (ch < 514) ? Wm1l[k * 514 + ch] : 0.f;
    } else {
        int c = ch - 544;
        val = (c < 514) ? Wm1l[(128 + k) * 514 + c] : 0.f;
    }
    Bp1[t] = (_Float16)val;
    if (t < 1088) bias1088[t] = (t < 514) ? bm1l[t] : 0.f;
    if (t < 544) w1c[t] = (_Float16)((t < 514) ? Wm1l[256 * 514 + t] : 0.f);
    if (t < 8704) {
        int i2 = t & 7, lane2 = (t >> 3) & 63, ks2 = t >> 9;
        int k2 = ks2 * 32 + ((lane2 >> 4) << 3) + i2;
        int c2 = lane2 & 15;
        W2p[t] = (_Float16)((k2 < 514) ? Wm2l[k2 * 16 + c2] : 0.f);
    }
}

// ---------------- batched generic B packer ----------------
__global__ void pack_generic(const float* __restrict__ Wall, size_t strideW, int K, int Nc,
                             _Float16* __restrict__ BpAll, size_t strideB) {
    int l = blockIdx.y;
    const float* W = Wall + (size_t)l * strideW;
    _Float16* Bp = BpAll + (size_t)l * strideB;
    int t = blockIdx.x * 256 + threadIdx.x;
    int i = t & 7;
    int lane = (t >> 3) & 63;
    int rest = t >> 9;
    int CB = Nc >> 4;
    int cb = rest % CB;
    int ks = rest / CB;
    int k = ks * 32 + ((lane >> 4) << 3) + i;
    int c = cb * 16 + (lane & 15);
    float val = (k < K) ? W[(size_t)k * Nc + c] : 0.f;
    Bp[t] = (_Float16)val;
}

// ---------------- table GEMM: A hi-only + fused agg zeroing ----------------
__global__ __launch_bounds__(256) void tab_gemm(
    const _Float16* __restrict__ Ahi,
    const _Float16* __restrict__ Bp, const float* __restrict__ bias,
    _Float16* __restrict__ TA, _Float16* __restrict__ TB, float* __restrict__ agg, int N) {
    {
        int base = blockIdx.x * 1024 + threadIdx.x;
#pragma unroll
        for (int q = 0; q < 4; ++q) {
            int idx = base + q * 256;
            if (idx < N * 16) agg[idx] = 0.f;
        }
    }
    int lane = threadIdx.x & 63;
    int wid = threadIdx.x >> 6;
    int row0 = blockIdx.x * 64 + wid * 16;
    if (row0 >= N) return;
    const size_t arow = (size_t)(row0 + (lane & 15)) * 128;
    const int ak = (lane >> 4) * 8;
    h16x8 ah[4];
#pragma unroll
    for (int ks = 0; ks < 4; ++ks)
        ah[ks] = *(const h16x8*)(Ahi + arow + ks * 32 + ak);
    int col16 = lane & 15;
    int rb = (lane >> 4) * 4;
    for (int cb = 0; cb < 68; ++cb) {
        f32x4 acc = {0.f, 0.f, 0.f, 0.f};
#pragma unroll
        for (int ks = 0; ks < 4; ++ks) {
            h16x8 bh = *(const h16x8*)(Bp + ((size_t)(ks * 68 + cb) * 64 + lane) * 8);
            acc = __builtin_amdgcn_mfma_f32_16x16x32_f16(ah[ks], bh, acc, 0, 0, 0);
        }
        int col = cb * 16 + col16;
        float bv = bias[col];
        if (cb < 34) {
#pragma unroll
            for (int i = 0; i < 4; ++i)
                TA[(size_t)(row0 + rb + i) * 544 + col] = (_Float16)(acc[i] + bv);
        } else {
#pragma unroll
            for (int i = 0; i < 4; ++i)
                TB[(size_t)(row0 + rb + i) * 544 + (col - 544)] = (_Float16)(acc[i] + bv);
        }
    }
}

// ---------------- generic 64-row A-in-regs GEMM (MODE 1: swish->t1 hi/lo; MODE 3: pool) ----------------
template <int KS, int CB, int MODE, bool LO>
__global__ __launch_bounds__(256) void gemmA(
    const _Float16* __restrict__ Ahi, const _Float16* __restrict__ Alo, int lda,
    const _Float16* __restrict__ Bp, const float* __restrict__ bias,
    _Float16* __restrict__ outB, _Float16* __restrict__ outB2, int ldoB,
    const int* __restrict__ batch, float* __restrict__ pooled, int N) {
    int lane = threadIdx.x & 63;
    int wid = threadIdx.x >> 6;
    int row0 = blockIdx.x * 64 + wid * 16;
    if (row0 >= N) return;
    const size_t arow = (size_t)(row0 + (lane & 15)) * lda;
    const int ak = (lane >> 4) * 8;
    h16x8 ah[KS], al[KS];
#pragma unroll
    for (int ks = 0; ks < KS; ++ks) {
        ah[ks] = *(const h16x8*)(Ahi + arow + ks * 32 + ak);
        if (LO) al[ks] = *(const h16x8*)(Alo + arow + ks * 32 + ak);
    }
    int col16 = lane & 15;
    int rb = (lane >> 4) * 4;
    for (int cb = 0; cb < CB; ++cb) {
        f32x4 acc = {0.f, 0.f, 0.f, 0.f};
#pragma unroll
        for (int ks = 0; ks < KS; ++ks) {
            h16x8 bh = *(const h16x8*)(Bp + ((size_t)(ks * CB + cb) * 64 + lane) * 8);
            acc = __builtin_amdgcn_mfma_f32_16x16x32_f16(ah[ks], bh, acc, 0, 0, 0);
            if (LO) acc = __builtin_amdgcn_mfma_f32_16x16x32_f16(al[ks], bh, acc, 0, 0, 0);
        }
        int col = cb * 16 + col16;
        float bv = bias[col];
#pragma unroll
        for (int i = 0; i < 4; ++i) {
            int row = row0 + rb + i;
            float v = acc[i] + bv;
            if (MODE == 1) {
                float s = swish_fast(v);
                _Float16 hi, lo;
                splitf16(s, hi, lo);
                outB[(size_t)row * ldoB + col] = hi;
                outB2[(size_t)row * ldoB + col] = lo;
            } else {
                unsafeAtomicAdd(&pooled[(size_t)batch[row] * 128 + col], v);
            }
        }
    }
}

// ---------------- fused up1+up2: u (hi-only) in LDS, residual epilogue ----------------
__global__ __launch_bounds__(256) void up_fused(
    const float* __restrict__ agg, const _Float16* __restrict__ Bp1,
    const float* __restrict__ b1, const _Float16* __restrict__ Bp2,
    const float* __restrict__ b2,
    float* __restrict__ hf, _Float16* __restrict__ hhi, int N) {
    __shared__ _Float16 sU[4][16][264];
    int lane = threadIdx.x & 63;
    int wid = threadIdx.x >> 6;
    int row0 = blockIdx.x * 64 + wid * 16;
    if (row0 >= N) return;
    int r = row0 + (lane & 15);
    const int ak = (lane >> 4) * 8;
    // phase 1: x = [agg(16) | h(128) | 0(16)] hi/lo fragments, up1 GEMM, swish -> u (hi) in LDS
    h16x8 ah[5], al[5];
#pragma unroll
    for (int ks = 0; ks < 5; ++ks) {
        int c0 = ks * 32 + ak;
        f32x4 v0, v1;
        if (c0 < 16) {
            v0 = *(const f32x4*)(agg + (size_t)r * 16 + c0);
            v1 = *(const f32x4*)(agg + (size_t)r * 16 + c0 + 4);
        } else if (c0 < 144) {
            v0 = *(const f32x4*)(hf + (size_t)r * 128 + c0 - 16);
            v1 = *(const f32x4*)(hf + (size_t)r * 128 + c0 - 12);
        } else {
            v0 = f32x4{0.f, 0.f, 0.f, 0.f};
            v1 = f32x4{0.f, 0.f, 0.f, 0.f};
        }
        h16x8 hi8, lo8;
#pragma unroll
        for (int jj = 0; jj < 8; ++jj) {
            float x = (jj < 4) ? v0[jj] : v1[jj - 4];
            _Float16 h, l;
            splitf16(x, h, l);
            hi8[jj] = h;
            lo8[jj] = l;
        }
        ah[ks] = hi8;
        al[ks] = lo8;
    }
    int col16 = lane & 15;
    int rb = (lane >> 4) * 4;
    for (int cb = 0; cb < 16; ++cb) {
        f32x4 acc = {0.f, 0.f, 0.f, 0.f};
#pragma unroll
        for (int ks = 0; ks < 5; ++ks) {
            h16x8 bh = *(const h16x8*)(Bp1 + ((size_t)(ks * 16 + cb) * 64 + lane) * 8);
            acc = __builtin_amdgcn_mfma_f32_16x16x32_f16(ah[ks], bh, acc, 0, 0, 0);
            acc = __builtin_amdgcn_mfma_f32_16x16x32_f16(al[ks], bh, acc, 0, 0, 0);
        }
        int col = cb * 16 + col16;
        float bv = b1[col];
#pragma unroll
        for (int i = 0; i < 4; ++i)
            sU[wid][rb + i][col] = (_Float16)swish_fast(acc[i] + bv);
    }
    __syncthreads();
    // phase 2: u(LDS, hi-only) @ Wu2 + resid -> h
    h16x8 ah2[8];
#pragma unroll
    for (int ks = 0; ks < 8; ++ks)
        ah2[ks] = *(const h16x8*)(&sU[wid][lane & 15][ks * 32 + ak]);
    for (int cb = 0; cb < 8; ++cb) {
        f32x4 acc = {0.f, 0.f, 0.f, 0.f};
#pragma unroll
        for (int ks = 0; ks < 8; ++ks) {
            h16x8 bh = *(const h16x8*)(Bp2 + ((size_t)(ks * 8 + cb) * 64 + lane) * 8);
            acc = __builtin_amdgcn_mfma_f32_16x16x32_f16(ah2[ks], bh, acc, 0, 0, 0);
        }
        int col = cb * 16 + col16;
        float bv = b2[col];
#pragma unroll
        for (int i = 0; i < 4; ++i) {
            int row = row0 + rb + i;
            float h = acc[i] + bv + hf[(size_t)row * 128 + col];
            hf[(size_t)row * 128 + col] = h;
            hhi[(size_t)row * 128 + col] = (_Float16)h;
        }
    }
}

// ---------------- edge kernel ----------------
__global__ __launch_bounds__(256) void edge_kernel(
    const _Float16* __restrict__ TA, const _Float16* __restrict__ TB,
    const _Float16* __restrict__ w1c, const _Float16* __restrict__ W2p,
    const float* __restrict__ bm2l,
    const int* __restrict__ srcS, const int* __restrict__ dstS,
    const float* __restrict__ n2S, float* __restrict__ agg) {
    __shared__ _Float16 sW[8704];
    __shared__ _Float16 sw1[544];
    for (int t = threadIdx.x; t < 1088; t += 256)
        ((h16x8*)sW)[t] = ((const h16x8*)W2p)[t];
    for (int t = threadIdx.x; t < 544; t += 256) sw1[t] = w1c[t];
    __syncthreads();

    int lane = threadIdx.x & 63;
    int wid = threadIdx.x >> 6;
    int ebase = blockIdx.x * 128 + wid * 32;
    int rr = lane & 15;
    int e0 = ebase + rr;
    int e1 = ebase + 16 + rr;
    int di0 = dstS[e0], si0 = srcS[e0];
    int di1 = dstS[e1], si1 = srcS[e1];
    _Float16 n20 = (_Float16)n2S[e0];
    _Float16 n21 = (_Float16)n2S[e1];
    const int ak = (lane >> 4) * 8;
    const _Float16* pa0 = TA + (size_t)di0 * 544 + ak;
    const _Float16* pb0 = TB + (size_t)si0 * 544 + ak;
    const _Float16* pa1 = TA + (size_t)di1 * 544 + ak;
    const _Float16* pb1 = TB + (size_t)si1 * 544 + ak;

    const _Float16 nl2e = (_Float16)(-1.44269504f);
    f32x4 acc0 = {0.f, 0.f, 0.f, 0.f};
    f32x4 acc1 = {0.f, 0.f, 0.f, 0.f};

    h16x8 bufA[16], bufB[16], bufT[4];

    auto issue4 = [&](h16x8* buf, int K) {
#pragma unroll
        for (int q = 0; q < 4; ++q) {
            buf[q * 4 + 0] = *(const h16x8*)(pa0 + (K + q) * 32);
            buf[q * 4 + 1] = *(const h16x8*)(pb0 + (K + q) * 32);
            buf[q * 4 + 2] = *(const h16x8*)(pa1 + (K + q) * 32);
            buf[q * 4 + 3] = *(const h16x8*)(pb1 + (K + q) * 32);
        }
    };
    auto step = [&](const h16x8* buf, int q, int ks) {
        h16x8 va0 = buf[q * 4 + 0], vb0 = buf[q * 4 + 1];
        h16x8 va1 = buf[q * 4 + 2], vb1 = buf[q * 4 + 3];
        h16x8 wv = *(const h16x8*)(sw1 + ks * 32 + ak);
        h16x8 x0 = va0 + vb0 + wv * n20;
        h16x8 ev0 = __builtin_elementwise_exp2(x0 * nl2e);
        h16x8 d0 = ev0 + (_Float16)1.0f;
        h16x8 r0;
#pragma unroll
        for (int j = 0; j < 8; ++j) r0[j] = __builtin_amdgcn_rcph(d0[j]);
        h16x8 m0 = x0 * r0;
        h16x8 x1 = va1 + vb1 + wv * n21;
        h16x8 ev1 = __builtin_elementwise_exp2(x1 * nl2e);
        h16x8 d1 = ev1 + (_Float16)1.0f;
        h16x8 r1;
#pragma unroll
        for (int j = 0; j < 8; ++j) r1[j] = __builtin_amdgcn_rcph(d1[j]);
        h16x8 m1 = x1 * r1;
        h16x8 bh = *(const h16x8*)(sW + (ks * 64 + lane) * 8);
        acc0 = __builtin_amdgcn_mfma_f32_16x16x32_f16(m0, bh, acc0, 0, 0, 0);
        acc1 = __builtin_amdgcn_mfma_f32_16x16x32_f16(m1, bh, acc1, 0, 0, 0);
    };

    issue4(bufA, 0);
    __builtin_amdgcn_sched_barrier(0);
    issue4(bufB, 4);
    __builtin_amdgcn_sched_barrier(0);
#pragma unroll
    for (int q = 0; q < 4; ++q) step(bufA, q, q);
    issue4(bufA, 8);
    __builtin_amdgcn_sched_barrier(0);
#pragma unroll
    for (int q = 0; q < 4; ++q) step(bufB, q, 4 + q);
    issue4(bufB, 12);
    __builtin_amdgcn_sched_barrier(0);
#pragma unroll
    for (int q = 0; q < 4; ++q) step(bufA, q, 8 + q);
    bufT[0] = *(const h16x8*)(pa0 + 16 * 32);
    bufT[1] = *(const h16x8*)(pb0 + 16 * 32);
    bufT[2] = *(const h16x8*)(pa1 + 16 * 32);
    bufT[3] = *(const h16x8*)(pb1 + 16 * 32);
    __builtin_amdgcn_sched_barrier(0);
#pragma unroll
    for (int q = 0; q < 4; ++q) step(bufB, q, 12 + q);
    step(bufT, 0, 16);

    int col = lane & 15;
    float b2 = bm2l[col];
#pragma unroll
    for (int i = 0; i < 4; ++i) {
        int ea = ebase + (lane >> 4) * 4 + i;
        float v0 = swish_fast(acc0[i] + b2);
        unsafeAtomicAdd(&agg[(size_t)dstS[ea] * 16 + col], v0);
        int eb = ea + 16;
        float v1 = swish_fast(acc1[i] + b2);
        unsafeAtomicAdd(&agg[(size_t)dstS[eb] * 16 + col], v1);
    }
}

// ---------------- readout ----------------
__global__ void readout(const float* __restrict__ pooled, const float* __restrict__ Wr1,
                        const float* __restrict__ br1, const float* __restrict__ Wr2,
                        const float* __restrict__ br2, float* __restrict__ out) {
    __shared__ float row[128];
    __shared__ float tt[128];
    int g = blockIdx.x;
    int t = threadIdx.x;
    row[t] = pooled[g * 128 + t];
    __syncthreads();
    float s = br1[t];
    for (int k = 0; k < 128; ++k) s += row[k] * Wr1[k * 128 + t];
    tt[t] = swish_fast(s);
    __syncthreads();
    if (t < 12) {
        float o = br2[t];
        for (int j = 0; j < 128; ++j) o += tt[j] * Wr2[j * 12 + t];
        out[g * 12 + t] = o;
    }
}

extern "C" void kernel_launch(void* const* d_in, const int* in_sizes, int n_in,
                              void* d_out, int out_size, void* d_ws, size_t ws_size,
                              hipStream_t stream) {
    const float* pos = (const float*)d_in[0];
    const int* z = (const int*)d_in[1];
    const int* ei = (const int*)d_in[2];
    const int* batch = (const int*)d_in[3];
    const float* emb = (const float*)d_in[4];
    const float* Wm1 = (const float*)d_in[5];
    const float* bm1 = (const float*)d_in[6];
    const float* Wm2 = (const float*)d_in[7];
    const float* bm2 = (const float*)d_in[8];
    const float* Wu1 = (const float*)d_in[9];
    const float* bu1 = (const float*)d_in[10];
    const float* Wu2 = (const float*)d_in[11];
    const float* bu2 = (const float*)d_in[12];
    const float* Wp1 = (const float*)d_in[13];
    const float* bp1v = (const float*)d_in[14];
    const float* Wp2 = (const float*)d_in[15];
    const float* bp2v = (const float*)d_in[16];
    const float* Wr1 = (const float*)d_in[17];
    const float* br1 = (const float*)d_in[18];
    const float* Wr2 = (const float*)d_in[19];
    const float* br2 = (const float*)d_in[20];

    const int N = in_sizes[0] / 3;   // 50000
    const int E = in_sizes[2] / 2;   // 800000
    const int G = out_size / 12;     // 1000
    const int* src = ei;
    const int* dstp = ei + E;
    const int stripeSz = (N + NSTRIPE - 1) / NSTRIPE;
    const int KN = NSTRIPE * N;
    const int NB = (KN + 255) / 256;

    char* ws = (char*)d_ws;
    size_t off = 0;
    auto alloc = [&](size_t bytes) -> char* {
        char* p = ws + off;
        off += (bytes + 255) & ~(size_t)255;
        return p;
    };
    _Float16* TA = (_Float16*)alloc((size_t)N * 544 * 2);
    _Float16* TB = (_Float16*)alloc((size_t)N * 544 * 2);
    float* hf = (float*)alloc((size_t)N * 128 * 4);
    _Float16* hhi = (_Float16*)alloc((size_t)N * 128 * 2);
    float* agg = (float*)alloc((size_t)N * 16 * 4);
    float* pooled = (float*)alloc((size_t)G * 128 * 4);
    int* hist = (int*)alloc((size_t)KN * 4);
    int* cursor = (int*)alloc((size_t)KN * 4);
    int* blocksum = (int*)alloc((size_t)NB * 4);
    int* perm = (int*)alloc((size_t)E * 4);
    int* srcS = (int*)alloc((size_t)E * 4);
    int* dstS = (int*)alloc((size_t)E * 4);
    float* n2S = (float*)alloc((size_t)E * 4);
    _Float16* Bp1A = (_Float16*)alloc((size_t)7 * 139264 * 2);
    float* biasA = (float*)alloc((size_t)7 * 1088 * 4);
    _Float16* w1cA = (_Float16*)alloc((size_t)7 * 544 * 2);
    _Float16* W2pA = (_Float16*)alloc((size_t)7 * 8704 * 2);
    _Float16* BpU1A = (_Float16*)alloc((size_t)7 * 40960 * 2);
    _Float16* BpU2A = (_Float16*)alloc((size_t)7 * 32768 * 2);
    _Float16* BpP1 = (_Float16*)alloc(16384 * 2);
    _Float16* BpP2 = (_Float16*)alloc(16384 * 2);

    // Post-loop t1 aliases into TB (dead after last edge pass).
    _Float16* t1hi = TB;
    _Float16* t1lo = TB + (size_t)N * 128;

    init_nodes<<<(N * 128) / 256, 256, 0, stream>>>(z, emb, hf, hhi, N);

    // one-time: counting sort of edges by (dst_stripe, src)
    hipMemsetAsync(hist, 0, (size_t)KN * 4, stream);
    hist_kernel<<<(E + 255) / 256, 256, 0, stream>>>(src, dstp, hist, E, N, stripeSz);
    scan_p1<<<NB, 256, 0, stream>>>(hist, blocksum, KN);
    scan_p2<<<1, 1024, 0, stream>>>(blocksum, NB);
    scan_p3<<<NB, 256, 0, stream>>>(hist, blocksum, cursor, KN);
    scatter_kernel<<<(E + 255) / 256, 256, 0, stream>>>(src, dstp, cursor, perm, E, N, stripeSz);
    reorder_kernel<<<(E + 255) / 256, 256, 0, stream>>>(perm, src, dstp, pos, srcS, dstS, n2S, E);

    // one-time: pack all layers' weights
    pack_msg1<<<dim3(139264 / 256, 7), 256, 0, stream>>>(Wm1, bm1, Wm2, Bp1A, biasA, w1cA, W2pA);
    pack_generic<<<dim3(160, 7), 256, 0, stream>>>(Wu1, (size_t)144 * 256, 144, 256, BpU1A, 40960);
    pack_generic<<<dim3(128, 7), 256, 0, stream>>>(Wu2, (size_t)256 * 128, 256, 128, BpU2A, 32768);
    pack_generic<<<dim3(64, 1), 256, 0, stream>>>(Wp1, 0, 128, 128, BpP1, 0);
    pack_generic<<<dim3(64, 1), 256, 0, stream>>>(Wp2, 0, 128, 128, BpP2, 0);
    hipMemsetAsync(pooled, 0, (size_t)G * 128 * 4, stream);

    const int gA = (N + 63) / 64;
    for (int l = 0; l < 7; ++l) {
        tab_gemm<<<gA, 256, 0, stream>>>(hhi, Bp1A + (size_t)l * 139264,
                                         biasA + (size_t)l * 1088, TA, TB, agg, N);
        edge_kernel<<<E / 128, 256, 0, stream>>>(TA, TB, w1cA + (size_t)l * 544,
                                                 W2pA + (size_t)l * 8704, bm2 + l * 16,
                                                 srcS, dstS, n2S, agg);
        up_fused<<<gA, 256, 0, stream>>>(agg, BpU1A + (size_t)l * 40960, bu1 + l * 256,
                                         BpU2A + (size_t)l * 32768, bu2 + l * 128,
                                         hf, hhi, N);
    }

    gemmA<4, 8, 1, false><<<gA, 256, 0, stream>>>(
        hhi, nullptr, 128, BpP1, bp1v,
        t1hi, t1lo, 128, nullptr, nullptr, N);
    gemmA<4, 8, 3, true><<<gA, 256, 0, stream>>>(
        t1hi, t1lo, 128, BpP2, bp2v,
        nullptr, nullptr, 0, batch, pooled, N);
    readout<<<G, 128, 0, stream>>>(pooled, Wr1, br1, Wr2, br2, (float*)d_out);
}

// Round 19
// 1892.203 us; speedup vs baseline: 1.1576x; 1.0064x over previous
//
#include <hip/hip_runtime.h>
#include <hip/hip_bf16.h>
#include <cstdint>
#include <cstddef>

typedef _Float16 h16x8 __attribute__((ext_vector_type(8)));
typedef float f32x4 __attribute__((ext_vector_type(4)));

#define NSTRIPE 2

__device__ __forceinline__ void splitf16(float v, _Float16& hi, _Float16& lo) {
    hi = (_Float16)v;
    lo = (_Float16)(v - (float)hi);
}
__device__ __forceinline__ float swish_fast(float x) {
    float e = __expf(-x);
    return x * __builtin_amdgcn_rcpf(1.0f + e);
}

// ---------------- init: h = emb[atomic[z]] ----------------
__global__ void init_nodes(const int* __restrict__ z, const float* __restrict__ emb,
                           float* __restrict__ hf, _Float16* __restrict__ hhi, int N) {
    int tid = blockIdx.x * 256 + threadIdx.x;
    int n = tid >> 7, f = tid & 127;
    int zv = z[n];
    int idx5 = (zv == 1) ? 0 : (zv - 5);
    float v = emb[idx5 * 128 + f];
    hf[tid] = v;
    hhi[tid] = (_Float16)v;
}

// ---------------- edge preprocessing: counting sort by (dst_stripe, src) ----------------
__device__ __forceinline__ int edge_key(int d, int s, int N, int stripeSz) {
    return (d / stripeSz) * N + s;
}

__global__ void hist_kernel(const int* __restrict__ src, const int* __restrict__ dst,
                            int* __restrict__ hist, int E, int N, int stripeSz) {
    int e = blockIdx.x * 256 + threadIdx.x;
    if (e < E) atomicAdd(&hist[edge_key(dst[e], src[e], N, stripeSz)], 1);
}

__global__ void scan_p1(const int* __restrict__ hist, int* __restrict__ blocksum, int KN) {
    __shared__ int s[256];
    int idx = blockIdx.x * 256 + threadIdx.x;
    int v = (idx < KN) ? hist[idx] : 0;
    s[threadIdx.x] = v;
    __syncthreads();
    for (int d = 128; d > 0; d >>= 1) {
        if (threadIdx.x < d) s[threadIdx.x] += s[threadIdx.x + d];
        __syncthreads();
    }
    if (threadIdx.x == 0) blocksum[blockIdx.x] = s[0];
}

__global__ void scan_p2(int* __restrict__ blocksum, int NB) {
    __shared__ int s[1024];
    int t = threadIdx.x;
    int v = (t < NB) ? blocksum[t] : 0;
    s[t] = v;
    __syncthreads();
    for (int d = 1; d < 1024; d <<= 1) {
        int x = (t >= d) ? s[t - d] : 0;
        __syncthreads();
        s[t] += x;
        __syncthreads();
    }
    if (t < NB) blocksum[t] = s[t] - v;  // exclusive
}

__global__ void scan_p3(const int* __restrict__ hist, const int* __restrict__ blocksum,
                        int* __restrict__ cursor, int KN) {
    __shared__ int s[256];
    int idx = blockIdx.x * 256 + threadIdx.x;
    int v = (idx < KN) ? hist[idx] : 0;
    s[threadIdx.x] = v;
    __syncthreads();
    for (int d = 1; d < 256; d <<= 1) {
        int x = (threadIdx.x >= d) ? s[threadIdx.x - d] : 0;
        __syncthreads();
        s[threadIdx.x] += x;
        __syncthreads();
    }
    if (idx < KN) cursor[idx] = blocksum[blockIdx.x] + s[threadIdx.x] - v;
}

__global__ void scatter_kernel(const int* __restrict__ src, const int* __restrict__ dst,
                               int* __restrict__ cursor, int* __restrict__ perm,
                               int E, int N, int stripeSz) {
    int e = blockIdx.x * 256 + threadIdx.x;
    if (e < E) {
        int p = atomicAdd(&cursor[edge_key(dst[e], src[e], N, stripeSz)], 1);
        perm[p] = e;
    }
}

__global__ void reorder_kernel(const int* __restrict__ perm, const int* __restrict__ src,
                               const int* __restrict__ dst, const float* __restrict__ pos,
                               int* __restrict__ srcS, int* __restrict__ dstS,
                               float* __restrict__ n2S, int E) {
    int i = blockIdx.x * 256 + threadIdx.x;
    if (i >= E) return;
    int e = perm[i];
    int si = src[e], di = dst[e];
    srcS[i] = si;
    dstS[i] = di;
    float dx = pos[si * 3 + 0] - pos[di * 3 + 0];
    float dy = pos[si * 3 + 1] - pos[di * 3 + 1];
    float dz = pos[si * 3 + 2] - pos[di * 3 + 2];
    n2S[i] = dx * dx + dy * dy + dz * dz;
}

// ---------------- batched pack W_msg1 + W_msg2 (all 7 layers) ----------------
__global__ void pack_msg1(const float* __restrict__ Wm1, const float* __restrict__ bm1,
                          const float* __restrict__ Wm2,
                          _Float16* __restrict__ Bp1A, float* __restrict__ biasA,
                          _Float16* __restrict__ w1cA, _Float16* __restrict__ W2pA) {
    int l = blockIdx.y;
    const float* Wm1l = Wm1 + (size_t)l * 257 * 514;
    const float* bm1l = bm1 + (size_t)l * 514;
    const float* Wm2l = Wm2 + (size_t)l * 514 * 16;
    _Float16* Bp1 = Bp1A + (size_t)l * 139264;
    float* bias1088 = biasA + (size_t)l * 1088;
    _Float16* w1c = w1cA + (size_t)l * 544;
    _Float16* W2p = W2pA + (size_t)l * 8704;

    int t = blockIdx.x * 256 + threadIdx.x;
    int i = t & 7;
    int lane = (t >> 3) & 63;
    int rest = t >> 9;
    int cb = rest % 68;
    int ks = rest / 68;
    int k = ks * 32 + ((lane >> 4) << 3) + i;
    int ch = cb * 16 + (lane & 15);
    float val;
    if (ch < 544) {
        val = (ch < 514) ? Wm1l[k * 514 + ch] : 0.f;
    } else {
        int c = ch - 544;
        val = (c < 514) ? Wm1l[(128 + k) * 514 + c] : 0.f;
    }
    Bp1[t] = (_Float16)val;
    if (t < 1088) bias1088[t] = (t < 514) ? bm1l[t] : 0.f;
    if (t < 544) w1c[t] = (_Float16)((t < 514) ? Wm1l[256 * 514 + t] : 0.f);
    if (t < 8704) {
        int i2 = t & 7, lane2 = (t >> 3) & 63, ks2 = t >> 9;
        int k2 = ks2 * 32 + ((lane2 >> 4) << 3) + i2;
        int c2 = lane2 & 15;
        W2p[t] = (_Float16)((k2 < 514) ? Wm2l[k2 * 16 + c2] : 0.f);
    }
}

// ---------------- batched generic B packer ----------------
__global__ void pack_generic(const float* __restrict__ Wall, size_t strideW, int K, int Nc,
                             _Float16* __restrict__ BpAll, size_t strideB) {
    int l = blockIdx.y;
    const float* W = Wall + (size_t)l * strideW;
    _Float16* Bp = BpAll + (size_t)l * strideB;
    int t = blockIdx.x * 256 + threadIdx.x;
    int i = t & 7;
    int lane = (t >> 3) & 63;
    int rest = t >> 9;
    int CB = Nc >> 4;
    int cb = rest % CB;
    int ks = rest / CB;
    int k = ks * 32 + ((lane >> 4) << 3) + i;
    int c = cb * 16 + (lane & 15);
    float val = (k < K) ? W[(size_t)k * Nc + c] : 0.f;
    Bp[t] = (_Float16)val;
}

// ---------------- table GEMM: A hi-only + fused agg zeroing ----------------
__global__ __launch_bounds__(256) void tab_gemm(
    const _Float16* __restrict__ Ahi,
    const _Float16* __restrict__ Bp, const float* __restrict__ bias,
    _Float16* __restrict__ TA, _Float16* __restrict__ TB, float* __restrict__ agg, int N) {
    {
        int base = blockIdx.x * 1024 + threadIdx.x;
#pragma unroll
        for (int q = 0; q < 4; ++q) {
            int idx = base + q * 256;
            if (idx < N * 16) agg[idx] = 0.f;
        }
    }
    int lane = threadIdx.x & 63;
    int wid = threadIdx.x >> 6;
    int row0 = blockIdx.x * 64 + wid * 16;
    if (row0 >= N) return;
    const size_t arow = (size_t)(row0 + (lane & 15)) * 128;
    const int ak = (lane >> 4) * 8;
    h16x8 ah[4];
#pragma unroll
    for (int ks = 0; ks < 4; ++ks)
        ah[ks] = *(const h16x8*)(Ahi + arow + ks * 32 + ak);
    int col16 = lane & 15;
    int rb = (lane >> 4) * 4;
    for (int cb = 0; cb < 68; ++cb) {
        f32x4 acc = {0.f, 0.f, 0.f, 0.f};
#pragma unroll
        for (int ks = 0; ks < 4; ++ks) {
            h16x8 bh = *(const h16x8*)(Bp + ((size_t)(ks * 68 + cb) * 64 + lane) * 8);
            acc = __builtin_amdgcn_mfma_f32_16x16x32_f16(ah[ks], bh, acc, 0, 0, 0);
        }
        int col = cb * 16 + col16;
        float bv = bias[col];
        if (cb < 34) {
#pragma unroll
            for (int i = 0; i < 4; ++i)
                TA[(size_t)(row0 + rb + i) * 544 + col] = (_Float16)(acc[i] + bv);
        } else {
#pragma unroll
            for (int i = 0; i < 4; ++i)
                TB[(size_t)(row0 + rb + i) * 544 + (col - 544)] = (_Float16)(acc[i] + bv);
        }
    }
}

// ---------------- generic 64-row A-in-regs GEMM, hi-only A ----------------
// MODE 1: swish -> outB (hi only); MODE 3: pooled atomic
template <int KS, int CB, int MODE>
__global__ __launch_bounds__(256) void gemmA(
    const _Float16* __restrict__ Ahi, int lda,
    const _Float16* __restrict__ Bp, const float* __restrict__ bias,
    _Float16* __restrict__ outB, int ldoB,
    const int* __restrict__ batch, float* __restrict__ pooled, int N) {
    int lane = threadIdx.x & 63;
    int wid = threadIdx.x >> 6;
    int row0 = blockIdx.x * 64 + wid * 16;
    if (row0 >= N) return;
    const size_t arow = (size_t)(row0 + (lane & 15)) * lda;
    const int ak = (lane >> 4) * 8;
    h16x8 ah[KS];
#pragma unroll
    for (int ks = 0; ks < KS; ++ks)
        ah[ks] = *(const h16x8*)(Ahi + arow + ks * 32 + ak);
    int col16 = lane & 15;
    int rb = (lane >> 4) * 4;
    for (int cb = 0; cb < CB; ++cb) {
        f32x4 acc = {0.f, 0.f, 0.f, 0.f};
#pragma unroll
        for (int ks = 0; ks < KS; ++ks) {
            h16x8 bh = *(const h16x8*)(Bp + ((size_t)(ks * CB + cb) * 64 + lane) * 8);
            acc = __builtin_amdgcn_mfma_f32_16x16x32_f16(ah[ks], bh, acc, 0, 0, 0);
        }
        int col = cb * 16 + col16;
        float bv = bias[col];
#pragma unroll
        for (int i = 0; i < 4; ++i) {
            int row = row0 + rb + i;
            float v = acc[i] + bv;
            if (MODE == 1) {
                outB[(size_t)row * ldoB + col] = (_Float16)swish_fast(v);
            } else {
                unsafeAtomicAdd(&pooled[(size_t)batch[row] * 128 + col], v);
            }
        }
    }
}

// ---------------- fused up1+up2: hi-only A, u (hi-only) in LDS, residual epilogue ----------------
__global__ __launch_bounds__(256) void up_fused(
    const float* __restrict__ agg, const _Float16* __restrict__ Bp1,
    const float* __restrict__ b1, const _Float16* __restrict__ Bp2,
    const float* __restrict__ b2,
    float* __restrict__ hf, _Float16* __restrict__ hhi, int N) {
    __shared__ _Float16 sU[4][16][264];
    int lane = threadIdx.x & 63;
    int wid = threadIdx.x >> 6;
    int row0 = blockIdx.x * 64 + wid * 16;
    if (row0 >= N) return;
    int r = row0 + (lane & 15);
    const int ak = (lane >> 4) * 8;
    // phase 1: x = [agg(16) | h(128) | 0(16)] hi-only fragments; up1 GEMM; swish -> u in LDS
    h16x8 ah[5];
#pragma unroll
    for (int ks = 0; ks < 5; ++ks) {
        int c0 = ks * 32 + ak;
        f32x4 v0, v1;
        if (c0 < 16) {
            v0 = *(const f32x4*)(agg + (size_t)r * 16 + c0);
            v1 = *(const f32x4*)(agg + (size_t)r * 16 + c0 + 4);
        } else if (c0 < 144) {
            v0 = *(const f32x4*)(hf + (size_t)r * 128 + c0 - 16);
            v1 = *(const f32x4*)(hf + (size_t)r * 128 + c0 - 12);
        } else {
            v0 = f32x4{0.f, 0.f, 0.f, 0.f};
            v1 = f32x4{0.f, 0.f, 0.f, 0.f};
        }
        h16x8 hi8;
#pragma unroll
        for (int jj = 0; jj < 8; ++jj)
            hi8[jj] = (_Float16)((jj < 4) ? v0[jj] : v1[jj - 4]);
        ah[ks] = hi8;
    }
    int col16 = lane & 15;
    int rb = (lane >> 4) * 4;
    for (int cb = 0; cb < 16; ++cb) {
        f32x4 acc = {0.f, 0.f, 0.f, 0.f};
#pragma unroll
        for (int ks = 0; ks < 5; ++ks) {
            h16x8 bh = *(const h16x8*)(Bp1 + ((size_t)(ks * 16 + cb) * 64 + lane) * 8);
            acc = __builtin_amdgcn_mfma_f32_16x16x32_f16(ah[ks], bh, acc, 0, 0, 0);
        }
        int col = cb * 16 + col16;
        float bv = b1[col];
#pragma unroll
        for (int i = 0; i < 4; ++i)
            sU[wid][rb + i][col] = (_Float16)swish_fast(acc[i] + bv);
    }
    __syncthreads();
    // phase 2: u(LDS, hi-only) @ Wu2 + resid -> h
    h16x8 ah2[8];
#pragma unroll
    for (int ks = 0; ks < 8; ++ks)
        ah2[ks] = *(const h16x8*)(&sU[wid][lane & 15][ks * 32 + ak]);
    for (int cb = 0; cb < 8; ++cb) {
        f32x4 acc = {0.f, 0.f, 0.f, 0.f};
#pragma unroll
        for (int ks = 0; ks < 8; ++ks) {
            h16x8 bh = *(const h16x8*)(Bp2 + ((size_t)(ks * 8 + cb) * 64 + lane) * 8);
            acc = __builtin_amdgcn_mfma_f32_16x16x32_f16(ah2[ks], bh, acc, 0, 0, 0);
        }
        int col = cb * 16 + col16;
        float bv = b2[col];
#pragma unroll
        for (int i = 0; i < 4; ++i) {
            int row = row0 + rb + i;
            float h = acc[i] + bv + hf[(size_t)row * 128 + col];
            hf[(size_t)row * 128 + col] = h;
            hhi[(size_t)row * 128 + col] = (_Float16)h;
        }
    }
}

// ---------------- edge kernel ----------------
__global__ __launch_bounds__(256) void edge_kernel(
    const _Float16* __restrict__ TA, const _Float16* __restrict__ TB,
    const _Float16* __restrict__ w1c, const _Float16* __restrict__ W2p,
    const float* __restrict__ bm2l,
    const int* __restrict__ srcS, const int* __restrict__ dstS,
    const float* __restrict__ n2S, float* __restrict__ agg) {
    __shared__ _Float16 sW[8704];
    __shared__ _Float16 sw1[544];
    for (int t = threadIdx.x; t < 1088; t += 256)
        ((h16x8*)sW)[t] = ((const h16x8*)W2p)[t];
    for (int t = threadIdx.x; t < 544; t += 256) sw1[t] = w1c[t];
    __syncthreads();

    int lane = threadIdx.x & 63;
    int wid = threadIdx.x >> 6;
    int ebase = blockIdx.x * 128 + wid * 32;
    int rr = lane & 15;
    int e0 = ebase + rr;
    int e1 = ebase + 16 + rr;
    int di0 = dstS[e0], si0 = srcS[e0];
    int di1 = dstS[e1], si1 = srcS[e1];
    _Float16 n20 = (_Float16)n2S[e0];
    _Float16 n21 = (_Float16)n2S[e1];
    const int ak = (lane >> 4) * 8;
    const _Float16* pa0 = TA + (size_t)di0 * 544 + ak;
    const _Float16* pb0 = TB + (size_t)si0 * 544 + ak;
    const _Float16* pa1 = TA + (size_t)di1 * 544 + ak;
    const _Float16* pb1 = TB + (size_t)si1 * 544 + ak;

    const _Float16 nl2e = (_Float16)(-1.44269504f);
    f32x4 acc0 = {0.f, 0.f, 0.f, 0.f};
    f32x4 acc1 = {0.f, 0.f, 0.f, 0.f};

    h16x8 bufA[16], bufB[16], bufT[4];

    auto issue4 = [&](h16x8* buf, int K) {
#pragma unroll
        for (int q = 0; q < 4; ++q) {
            buf[q * 4 + 0] = *(const h16x8*)(pa0 + (K + q) * 32);
            buf[q * 4 + 1] = *(const h16x8*)(pb0 + (K + q) * 32);
            buf[q * 4 + 2] = *(const h16x8*)(pa1 + (K + q) * 32);
            buf[q * 4 + 3] = *(const h16x8*)(pb1 + (K + q) * 32);
        }
    };
    auto step = [&](const h16x8* buf, int q, int ks) {
        h16x8 va0 = buf[q * 4 + 0], vb0 = buf[q * 4 + 1];
        h16x8 va1 = buf[q * 4 + 2], vb1 = buf[q * 4 + 3];
        h16x8 wv = *(const h16x8*)(sw1 + ks * 32 + ak);
        h16x8 x0 = va0 + vb0 + wv * n20;
        h16x8 ev0 = __builtin_elementwise_exp2(x0 * nl2e);
        h16x8 d0 = ev0 + (_Float16)1.0f;
        h16x8 r0;
#pragma unroll
        for (int j = 0; j < 8; ++j) r0[j] = __builtin_amdgcn_rcph(d0[j]);
        h16x8 m0 = x0 * r0;
        h16x8 x1 = va1 + vb1 + wv * n21;
        h16x8 ev1 = __builtin_elementwise_exp2(x1 * nl2e);
        h16x8 d1 = ev1 + (_Float16)1.0f;
        h16x8 r1;
#pragma unroll
        for (int j = 0; j < 8; ++j) r1[j] = __builtin_amdgcn_rcph(d1[j]);
        h16x8 m1 = x1 * r1;
        h16x8 bh = *(const h16x8*)(sW + (ks * 64 + lane) * 8);
        acc0 = __builtin_amdgcn_mfma_f32_16x16x32_f16(m0, bh, acc0, 0, 0, 0);
        acc1 = __builtin_amdgcn_mfma_f32_16x16x32_f16(m1, bh, acc1, 0, 0, 0);
    };

    issue4(bufA, 0);
    __builtin_amdgcn_sched_barrier(0);
    issue4(bufB, 4);
    __builtin_amdgcn_sched_barrier(0);
#pragma unroll
    for (int q = 0; q < 4; ++q) step(bufA, q, q);
    issue4(bufA, 8);
    __builtin_amdgcn_sched_barrier(0);
#pragma unroll
    for (int q = 0; q < 4; ++q) step(bufB, q, 4 + q);
    issue4(bufB, 12);
    __builtin_amdgcn_sched_barrier(0);
#pragma unroll
    for (int q = 0; q < 4; ++q) step(bufA, q, 8 + q);
    bufT[0] = *(const h16x8*)(pa0 + 16 * 32);
    bufT[1] = *(const h16x8*)(pb0 + 16 * 32);
    bufT[2] = *(const h16x8*)(pa1 + 16 * 32);
    bufT[3] = *(const h16x8*)(pb1 + 16 * 32);
    __builtin_amdgcn_sched_barrier(0);
#pragma unroll
    for (int q = 0; q < 4; ++q) step(bufB, q, 12 + q);
    step(bufT, 0, 16);

    int col = lane & 15;
    float b2 = bm2l[col];
#pragma unroll
    for (int i = 0; i < 4; ++i) {
        int ea = ebase + (lane >> 4) * 4 + i;
        float v0 = swish_fast(acc0[i] + b2);
        unsafeAtomicAdd(&agg[(size_t)dstS[ea] * 16 + col], v0);
        int eb = ea + 16;
        float v1 = swish_fast(acc1[i] + b2);
        unsafeAtomicAdd(&agg[(size_t)dstS[eb] * 16 + col], v1);
    }
}

// ---------------- readout ----------------
__global__ void readout(const float* __restrict__ pooled, const float* __restrict__ Wr1,
                        const float* __restrict__ br1, const float* __restrict__ Wr2,
                        const float* __restrict__ br2, float* __restrict__ out) {
    __shared__ float row[128];
    __shared__ float tt[128];
    int g = blockIdx.x;
    int t = threadIdx.x;
    row[t] = pooled[g * 128 + t];
    __syncthreads();
    float s = br1[t];
    for (int k = 0; k < 128; ++k) s += row[k] * Wr1[k * 128 + t];
    tt[t] = swish_fast(s);
    __syncthreads();
    if (t < 12) {
        float o = br2[t];
        for (int j = 0; j < 128; ++j) o += tt[j] * Wr2[j * 12 + t];
        out[g * 12 + t] = o;
    }
}

extern "C" void kernel_launch(void* const* d_in, const int* in_sizes, int n_in,
                              void* d_out, int out_size, void* d_ws, size_t ws_size,
                              hipStream_t stream) {
    const float* pos = (const float*)d_in[0];
    const int* z = (const int*)d_in[1];
    const int* ei = (const int*)d_in[2];
    const int* batch = (const int*)d_in[3];
    const float* emb = (const float*)d_in[4];
    const float* Wm1 = (const float*)d_in[5];
    const float* bm1 = (const float*)d_in[6];
    const float* Wm2 = (const float*)d_in[7];
    const float* bm2 = (const float*)d_in[8];
    const float* Wu1 = (const float*)d_in[9];
    const float* bu1 = (const float*)d_in[10];
    const float* Wu2 = (const float*)d_in[11];
    const float* bu2 = (const float*)d_in[12];
    const float* Wp1 = (const float*)d_in[13];
    const float* bp1v = (const float*)d_in[14];
    const float* Wp2 = (const float*)d_in[15];
    const float* bp2v = (const float*)d_in[16];
    const float* Wr1 = (const float*)d_in[17];
    const float* br1 = (const float*)d_in[18];
    const float* Wr2 = (const float*)d_in[19];
    const float* br2 = (const float*)d_in[20];

    const int N = in_sizes[0] / 3;   // 50000
    const int E = in_sizes[2] / 2;   // 800000
    const int G = out_size / 12;     // 1000
    const int* src = ei;
    const int* dstp = ei + E;
    const int stripeSz = (N + NSTRIPE - 1) / NSTRIPE;
    const int KN = NSTRIPE * N;
    const int NB = (KN + 255) / 256;

    char* ws = (char*)d_ws;
    size_t off = 0;
    auto alloc = [&](size_t bytes) -> char* {
        char* p = ws + off;
        off += (bytes + 255) & ~(size_t)255;
        return p;
    };
    _Float16* TA = (_Float16*)alloc((size_t)N * 544 * 2);
    _Float16* TB = (_Float16*)alloc((size_t)N * 544 * 2);
    float* hf = (float*)alloc((size_t)N * 128 * 4);
    _Float16* hhi = (_Float16*)alloc((size_t)N * 128 * 2);
    float* agg = (float*)alloc((size_t)N * 16 * 4);
    float* pooled = (float*)alloc((size_t)G * 128 * 4);
    int* hist = (int*)alloc((size_t)KN * 4);
    int* cursor = (int*)alloc((size_t)KN * 4);
    int* blocksum = (int*)alloc((size_t)NB * 4);
    int* perm = (int*)alloc((size_t)E * 4);
    int* srcS = (int*)alloc((size_t)E * 4);
    int* dstS = (int*)alloc((size_t)E * 4);
    float* n2S = (float*)alloc((size_t)E * 4);
    _Float16* Bp1A = (_Float16*)alloc((size_t)7 * 139264 * 2);
    float* biasA = (float*)alloc((size_t)7 * 1088 * 4);
    _Float16* w1cA = (_Float16*)alloc((size_t)7 * 544 * 2);
    _Float16* W2pA = (_Float16*)alloc((size_t)7 * 8704 * 2);
    _Float16* BpU1A = (_Float16*)alloc((size_t)7 * 40960 * 2);
    _Float16* BpU2A = (_Float16*)alloc((size_t)7 * 32768 * 2);
    _Float16* BpP1 = (_Float16*)alloc(16384 * 2);
    _Float16* BpP2 = (_Float16*)alloc(16384 * 2);

    // Post-loop t1 aliases into TB (dead after last edge pass).
    _Float16* t1hi = TB;

    init_nodes<<<(N * 128) / 256, 256, 0, stream>>>(z, emb, hf, hhi, N);

    // one-time: counting sort of edges by (dst_stripe, src)
    hipMemsetAsync(hist, 0, (size_t)KN * 4, stream);
    hist_kernel<<<(E + 255) / 256, 256, 0, stream>>>(src, dstp, hist, E, N, stripeSz);
    scan_p1<<<NB, 256, 0, stream>>>(hist, blocksum, KN);
    scan_p2<<<1, 1024, 0, stream>>>(blocksum, NB);
    scan_p3<<<NB, 256, 0, stream>>>(hist, blocksum, cursor, KN);
    scatter_kernel<<<(E + 255) / 256, 256, 0, stream>>>(src, dstp, cursor, perm, E, N, stripeSz);
    reorder_kernel<<<(E + 255) / 256, 256, 0, stream>>>(perm, src, dstp, pos, srcS, dstS, n2S, E);

    // one-time: pack all layers' weights
    pack_msg1<<<dim3(139264 / 256, 7), 256, 0, stream>>>(Wm1, bm1, Wm2, Bp1A, biasA, w1cA, W2pA);
    pack_generic<<<dim3(160, 7), 256, 0, stream>>>(Wu1, (size_t)144 * 256, 144, 256, BpU1A, 40960);
    pack_generic<<<dim3(128, 7), 256, 0, stream>>>(Wu2, (size_t)256 * 128, 256, 128, BpU2A, 32768);
    pack_generic<<<dim3(64, 1), 256, 0, stream>>>(Wp1, 0, 128, 128, BpP1, 0);
    pack_generic<<<dim3(64, 1), 256, 0, stream>>>(Wp2, 0, 128, 128, BpP2, 0);
    hipMemsetAsync(pooled, 0, (size_t)G * 128 * 4, stream);

    const int gA = (N + 63) / 64;
    for (int l = 0; l < 7; ++l) {
        tab_gemm<<<gA, 256, 0, stream>>>(hhi, Bp1A + (size_t)l * 139264,
                                         biasA + (size_t)l * 1088, TA, TB, agg, N);
        edge_kernel<<<E / 128, 256, 0, stream>>>(TA, TB, w1cA + (size_t)l * 544,
                                                 W2pA + (size_t)l * 8704, bm2 + l * 16,
                                                 srcS, dstS, n2S, agg);
        up_fused<<<gA, 256, 0, stream>>>(agg, BpU1A + (size_t)l * 40960, bu1 + l * 256,
                                         BpU2A + (size_t)l * 32768, bu2 + l * 128,
                                         hf, hhi, N);
    }

    gemmA<4, 8, 1><<<gA, 256, 0, stream>>>(
        hhi, 128, BpP1, bp1v, t1hi, 128, nullptr, nullptr, N);
    gemmA<4, 8, 3><<<gA, 256, 0, stream>>>(
        t1hi, 128, BpP2, bp2v, nullptr, 0, batch, pooled, N);
    readout<<<G, 128, 0, stream>>>(pooled, Wr1, br1, Wr2, br2, (float*)d_out);
}

// Round 20
// 1864.210 us; speedup vs baseline: 1.1750x; 1.0150x over previous
//
#include <hip/hip_runtime.h>
#include <hip/hip_bf16.h>
#include <cstdint>
#include <cstddef>

typedef _Float16 h16x8 __attribute__((ext_vector_type(8)));
typedef float f32x4 __attribute__((ext_vector_type(4)));

#define NSTRIPE 2

__device__ __forceinline__ float swish_fast(float x) {
    float e = __expf(-x);
    return x * __builtin_amdgcn_rcpf(1.0f + e);
}

// ---------------- init: h = emb[atomic[z]] ----------------
__global__ void init_nodes(const int* __restrict__ z, const float* __restrict__ emb,
                           float* __restrict__ hf, _Float16* __restrict__ hhi, int N) {
    int tid = blockIdx.x * 256 + threadIdx.x;
    int n = tid >> 7, f = tid & 127;
    int zv = z[n];
    int idx5 = (zv == 1) ? 0 : (zv - 5);
    float v = emb[idx5 * 128 + f];
    hf[tid] = v;
    hhi[tid] = (_Float16)v;
}

// ---------------- edge preprocessing: counting sort by (dst_stripe, src) ----------------
__device__ __forceinline__ int edge_key(int d, int s, int N, int stripeSz) {
    return (d / stripeSz) * N + s;
}

__global__ void hist_kernel(const int* __restrict__ src, const int* __restrict__ dst,
                            int* __restrict__ hist, int E, int N, int stripeSz) {
    int e = blockIdx.x * 256 + threadIdx.x;
    if (e < E) atomicAdd(&hist[edge_key(dst[e], src[e], N, stripeSz)], 1);
}

__global__ void scan_p1(const int* __restrict__ hist, int* __restrict__ blocksum, int KN) {
    __shared__ int s[256];
    int idx = blockIdx.x * 256 + threadIdx.x;
    int v = (idx < KN) ? hist[idx] : 0;
    s[threadIdx.x] = v;
    __syncthreads();
    for (int d = 128; d > 0; d >>= 1) {
        if (threadIdx.x < d) s[threadIdx.x] += s[threadIdx.x + d];
        __syncthreads();
    }
    if (threadIdx.x == 0) blocksum[blockIdx.x] = s[0];
}

__global__ void scan_p2(int* __restrict__ blocksum, int NB) {
    __shared__ int s[1024];
    int t = threadIdx.x;
    int v = (t < NB) ? blocksum[t] : 0;
    s[t] = v;
    __syncthreads();
    for (int d = 1; d < 1024; d <<= 1) {
        int x = (t >= d) ? s[t - d] : 0;
        __syncthreads();
        s[t] += x;
        __syncthreads();
    }
    if (t < NB) blocksum[t] = s[t] - v;  // exclusive
}

__global__ void scan_p3(const int* __restrict__ hist, const int* __restrict__ blocksum,
                        int* __restrict__ cursor, int KN) {
    __shared__ int s[256];
    int idx = blockIdx.x * 256 + threadIdx.x;
    int v = (idx < KN) ? hist[idx] : 0;
    s[threadIdx.x] = v;
    __syncthreads();
    for (int d = 1; d < 256; d <<= 1) {
        int x = (threadIdx.x >= d) ? s[threadIdx.x - d] : 0;
        __syncthreads();
        s[threadIdx.x] += x;
        __syncthreads();
    }
    if (idx < KN) cursor[idx] = blocksum[blockIdx.x] + s[threadIdx.x] - v;
}

__global__ void scatter_kernel(const int* __restrict__ src, const int* __restrict__ dst,
                               int* __restrict__ cursor, int* __restrict__ perm,
                               int E, int N, int stripeSz) {
    int e = blockIdx.x * 256 + threadIdx.x;
    if (e < E) {
        int p = atomicAdd(&cursor[edge_key(dst[e], src[e], N, stripeSz)], 1);
        perm[p] = e;
    }
}

__global__ void reorder_kernel(const int* __restrict__ perm, const int* __restrict__ src,
                               const int* __restrict__ dst, const float* __restrict__ pos,
                               int* __restrict__ srcS, int* __restrict__ dstS,
                               float* __restrict__ n2S, int E) {
    int i = blockIdx.x * 256 + threadIdx.x;
    if (i >= E) return;
    int e = perm[i];
    int si = src[e], di = dst[e];
    srcS[i] = si;
    dstS[i] = di;
    float dx = pos[si * 3 + 0] - pos[di * 3 + 0];
    float dy = pos[si * 3 + 1] - pos[di * 3 + 1];
    float dz = pos[si * 3 + 2] - pos[di * 3 + 2];
    n2S[i] = dx * dx + dy * dy + dz * dz;
}

// ---------------- batched pack W_msg1 + W_msg2 (all 7 layers) ----------------
__global__ void pack_msg1(const float* __restrict__ Wm1, const float* __restrict__ bm1,
                          const float* __restrict__ Wm2,
                          _Float16* __restrict__ Bp1A, float* __restrict__ biasA,
                          _Float16* __restrict__ w1cA, _Float16* __restrict__ W2pA) {
    int l = blockIdx.y;
    const float* Wm1l = Wm1 + (size_t)l * 257 * 514;
    const float* bm1l = bm1 + (size_t)l * 514;
    const float* Wm2l = Wm2 + (size_t)l * 514 * 16;
    _Float16* Bp1 = Bp1A + (size_t)l * 139264;
    float* bias1088 = biasA + (size_t)l * 1088;
    _Float16* w1c = w1cA + (size_t)l * 544;
    _Float16* W2p = W2pA + (size_t)l * 8704;

    int t = blockIdx.x * 256 + threadIdx.x;
    int i = t & 7;
    int lane = (t >> 3) & 63;
    int rest = t >> 9;
    int cb = rest % 68;
    int ks = rest / 68;
    int k = ks * 32 + ((lane >> 4) << 3) + i;
    int ch = cb * 16 + (lane & 15);
    float val;
    if (ch < 544) {
        val = (ch < 514) ? Wm1l[k * 514 + ch] : 0.f;
    } else {
        int c = ch - 544;
        val = (c < 514) ? Wm1l[(128 + k) * 514 + c] : 0.f;
    }
    Bp1[t] = (_Float16)val;
    if (t < 1088) bias1088[t] = (t < 514) ? bm1l[t] : 0.f;
    if (t < 544) w1c[t] = (_Float16)((t < 514) ? Wm1l[256 * 514 + t] : 0.f);
    if (t < 8704) {
        int i2 = t & 7, lane2 = (t >> 3) & 63, ks2 = t >> 9;
        int k2 = ks2 * 32 + ((lane2 >> 4) << 3) + i2;
        int c2 = lane2 & 15;
        W2p[t] = (_Float16)((k2 < 514) ? Wm2l[k2 * 16 + c2] : 0.f);
    }
}

// ---------------- batched generic B packer ----------------
__global__ void pack_generic(const float* __restrict__ Wall, size_t strideW, int K, int Nc,
                             _Float16* __restrict__ BpAll, size_t strideB) {
    int l = blockIdx.y;
    const float* W = Wall + (size_t)l * strideW;
    _Float16* Bp = BpAll + (size_t)l * strideB;
    int t = blockIdx.x * 256 + threadIdx.x;
    int i = t & 7;
    int lane = (t >> 3) & 63;
    int rest = t >> 9;
    int CB = Nc >> 4;
    int cb = rest % CB;
    int ks = rest / CB;
    int k = ks * 32 + ((lane >> 4) << 3) + i;
    int c = cb * 16 + (lane & 15);
    float val = (k < K) ? W[(size_t)k * Nc + c] : 0.f;
    Bp[t] = (_Float16)val;
}

// ---------------- standalone table GEMM (layer 0 only): A hi-only + agg zeroing ----------------
__global__ __launch_bounds__(256) void tab_gemm(
    const _Float16* __restrict__ Ahi,
    const _Float16* __restrict__ Bp, const float* __restrict__ bias,
    _Float16* __restrict__ TA, _Float16* __restrict__ TB, float* __restrict__ agg, int N) {
    {
        int base = blockIdx.x * 1024 + threadIdx.x;
#pragma unroll
        for (int q = 0; q < 4; ++q) {
            int idx = base + q * 256;
            if (idx < N * 16) agg[idx] = 0.f;
        }
    }
    int lane = threadIdx.x & 63;
    int wid = threadIdx.x >> 6;
    int row0 = blockIdx.x * 64 + wid * 16;
    if (row0 >= N) return;
    const size_t arow = (size_t)(row0 + (lane & 15)) * 128;
    const int ak = (lane >> 4) * 8;
    h16x8 ah[4];
#pragma unroll
    for (int ks = 0; ks < 4; ++ks)
        ah[ks] = *(const h16x8*)(Ahi + arow + ks * 32 + ak);
    int col16 = lane & 15;
    int rb = (lane >> 4) * 4;
    for (int cb = 0; cb < 68; ++cb) {
        f32x4 acc = {0.f, 0.f, 0.f, 0.f};
#pragma unroll
        for (int ks = 0; ks < 4; ++ks) {
            h16x8 bh = *(const h16x8*)(Bp + ((size_t)(ks * 68 + cb) * 64 + lane) * 8);
            acc = __builtin_amdgcn_mfma_f32_16x16x32_f16(ah[ks], bh, acc, 0, 0, 0);
        }
        int col = cb * 16 + col16;
        float bv = bias[col];
        if (cb < 34) {
#pragma unroll
            for (int i = 0; i < 4; ++i)
                TA[(size_t)(row0 + rb + i) * 544 + col] = (_Float16)(acc[i] + bv);
        } else {
#pragma unroll
            for (int i = 0; i < 4; ++i)
                TB[(size_t)(row0 + rb + i) * 544 + (col - 544)] = (_Float16)(acc[i] + bv);
        }
    }
}

// ---------------- fused node kernel: up1 -> up2(+resid) -> {next tab | proj1+proj2+pool} ----------------
// LDS: single sU[4][16][264] (33.8 KB, 4 blocks/CU).
// phase1: u = swish(x@Wu1+b1) -> sU cols 0..255
// phase2: h = u@Wu2+b2+resid; MODE0: hf=h; h (f16) -> sU cols 0..127
// MODE0 phase3: next-layer table GEMM (A=h from LDS) -> TA/TB; agg re-zeroed after phase1
// MODE1 phase3: t1 = swish(h@Wp1+bp1) -> sU cols 128..255; phase4: pooled += t1@Wp2+bp2
template <int MODE>
__global__ __launch_bounds__(256) void up_tab(
    const float* __restrict__ agg, float* __restrict__ hf,
    const _Float16* __restrict__ Bp1, const float* __restrict__ b1,
    const _Float16* __restrict__ Bp2, const float* __restrict__ b2,
    const _Float16* __restrict__ BpX1, const float* __restrict__ bX1,
    const _Float16* __restrict__ BpX2, const float* __restrict__ bX2,
    _Float16* __restrict__ TA, _Float16* __restrict__ TB,
    const int* __restrict__ batch, float* __restrict__ pooled, int N) {
    __shared__ _Float16 sU[4][16][264];
    int lane = threadIdx.x & 63;
    int wid = threadIdx.x >> 6;
    int row0 = blockIdx.x * 64 + wid * 16;
    int col16 = lane & 15;
    int rb = (lane >> 4) * 4;
    const int ak = (lane >> 4) * 8;

    if (row0 < N) {
        int r = row0 + col16;
        // ---- phase 1: up1 (hi-only A) ----
        h16x8 ah[5];
#pragma unroll
        for (int ks = 0; ks < 5; ++ks) {
            int c0 = ks * 32 + ak;
            f32x4 v0, v1;
            if (c0 < 16) {
                v0 = *(const f32x4*)(agg + (size_t)r * 16 + c0);
                v1 = *(const f32x4*)(agg + (size_t)r * 16 + c0 + 4);
            } else if (c0 < 144) {
                v0 = *(const f32x4*)(hf + (size_t)r * 128 + c0 - 16);
                v1 = *(const f32x4*)(hf + (size_t)r * 128 + c0 - 12);
            } else {
                v0 = f32x4{0.f, 0.f, 0.f, 0.f};
                v1 = f32x4{0.f, 0.f, 0.f, 0.f};
            }
            h16x8 hi8;
#pragma unroll
            for (int jj = 0; jj < 8; ++jj)
                hi8[jj] = (_Float16)((jj < 4) ? v0[jj] : v1[jj - 4]);
            ah[ks] = hi8;
        }
        for (int cb = 0; cb < 16; ++cb) {
            f32x4 acc = {0.f, 0.f, 0.f, 0.f};
#pragma unroll
            for (int ks = 0; ks < 5; ++ks) {
                h16x8 bh = *(const h16x8*)(Bp1 + ((size_t)(ks * 16 + cb) * 64 + lane) * 8);
                acc = __builtin_amdgcn_mfma_f32_16x16x32_f16(ah[ks], bh, acc, 0, 0, 0);
            }
            int col = cb * 16 + col16;
            float bv = b1[col];
#pragma unroll
            for (int i = 0; i < 4; ++i)
                sU[wid][rb + i][col] = (_Float16)swish_fast(acc[i] + bv);
        }
    }
    __syncthreads();
    // agg re-zero for next layer's edge pass (own rows; own phase-1 reads are done)
    if (MODE == 0) {
        int base = blockIdx.x * 1024 + threadIdx.x;
#pragma unroll
        for (int q = 0; q < 4; ++q) {
            int idx = base + q * 256;
            if (idx < N * 16) ((float*)agg)[idx] = 0.f;
        }
    }
    if (row0 >= N) return;
    // ---- phase 2: up2 + resid -> h (regs -> sU cols 0..127) ----
    h16x8 ah2[8];
#pragma unroll
    for (int ks = 0; ks < 8; ++ks)
        ah2[ks] = *(const h16x8*)(&sU[wid][col16][ks * 32 + ak]);
    for (int cb = 0; cb < 8; ++cb) {
        f32x4 acc = {0.f, 0.f, 0.f, 0.f};
#pragma unroll
        for (int ks = 0; ks < 8; ++ks) {
            h16x8 bh = *(const h16x8*)(Bp2 + ((size_t)(ks * 8 + cb) * 64 + lane) * 8);
            acc = __builtin_amdgcn_mfma_f32_16x16x32_f16(ah2[ks], bh, acc, 0, 0, 0);
        }
        int col = cb * 16 + col16;
        float bv = b2[col];
#pragma unroll
        for (int i = 0; i < 4; ++i) {
            int row = row0 + rb + i;
            float h = acc[i] + bv + hf[(size_t)row * 128 + col];
            if (MODE == 0) hf[(size_t)row * 128 + col] = h;
            sU[wid][rb + i][col] = (_Float16)h;
        }
    }
    __syncthreads();
    if (MODE == 0) {
        // ---- phase 3: next layer's table GEMM (A = h from LDS) ----
        h16x8 ah3[4];
#pragma unroll
        for (int ks = 0; ks < 4; ++ks)
            ah3[ks] = *(const h16x8*)(&sU[wid][col16][ks * 32 + ak]);
        for (int cb = 0; cb < 68; ++cb) {
            f32x4 acc = {0.f, 0.f, 0.f, 0.f};
#pragma unroll
            for (int ks = 0; ks < 4; ++ks) {
                h16x8 bh = *(const h16x8*)(BpX1 + ((size_t)(ks * 68 + cb) * 64 + lane) * 8);
                acc = __builtin_amdgcn_mfma_f32_16x16x32_f16(ah3[ks], bh, acc, 0, 0, 0);
            }
            int col = cb * 16 + col16;
            float bv = bX1[col];
            if (cb < 34) {
#pragma unroll
                for (int i = 0; i < 4; ++i)
                    TA[(size_t)(row0 + rb + i) * 544 + col] = (_Float16)(acc[i] + bv);
            } else {
#pragma unroll
                for (int i = 0; i < 4; ++i)
                    TB[(size_t)(row0 + rb + i) * 544 + (col - 544)] = (_Float16)(acc[i] + bv);
            }
        }
    } else {
        // ---- phase 3: proj1 -> t1 (sU cols 128..255) ----
        h16x8 ah3[4];
#pragma unroll
        for (int ks = 0; ks < 4; ++ks)
            ah3[ks] = *(const h16x8*)(&sU[wid][col16][ks * 32 + ak]);
        for (int cb = 0; cb < 8; ++cb) {
            f32x4 acc = {0.f, 0.f, 0.f, 0.f};
#pragma unroll
            for (int ks = 0; ks < 4; ++ks) {
                h16x8 bh = *(const h16x8*)(BpX1 + ((size_t)(ks * 8 + cb) * 64 + lane) * 8);
                acc = __builtin_amdgcn_mfma_f32_16x16x32_f16(ah3[ks], bh, acc, 0, 0, 0);
            }
            int col = cb * 16 + col16;
            float bv = bX1[col];
#pragma unroll
            for (int i = 0; i < 4; ++i)
                sU[wid][rb + i][128 + col] = (_Float16)swish_fast(acc[i] + bv);
        }
        __syncthreads();
        // ---- phase 4: proj2 + pooled atomic ----
        h16x8 ah4[4];
#pragma unroll
        for (int ks = 0; ks < 4; ++ks)
            ah4[ks] = *(const h16x8*)(&sU[wid][col16][128 + ks * 32 + ak]);
        for (int cb = 0; cb < 8; ++cb) {
            f32x4 acc = {0.f, 0.f, 0.f, 0.f};
#pragma unroll
            for (int ks = 0; ks < 4; ++ks) {
                h16x8 bh = *(const h16x8*)(BpX2 + ((size_t)(ks * 8 + cb) * 64 + lane) * 8);
                acc = __builtin_amdgcn_mfma_f32_16x16x32_f16(ah4[ks], bh, acc, 0, 0, 0);
            }
            int col = cb * 16 + col16;
            float bv = bX2[col];
#pragma unroll
            for (int i = 0; i < 4; ++i) {
                int row = row0 + rb + i;
                unsafeAtomicAdd(&pooled[(size_t)batch[row] * 128 + col], acc[i] + bv);
            }
        }
    }
}

// ---------------- edge kernel ----------------
__global__ __launch_bounds__(256) void edge_kernel(
    const _Float16* __restrict__ TA, const _Float16* __restrict__ TB,
    const _Float16* __restrict__ w1c, const _Float16* __restrict__ W2p,
    const float* __restrict__ bm2l,
    const int* __restrict__ srcS, const int* __restrict__ dstS,
    const float* __restrict__ n2S, float* __restrict__ agg) {
    __shared__ _Float16 sW[8704];
    __shared__ _Float16 sw1[544];
    for (int t = threadIdx.x; t < 1088; t += 256)
        ((h16x8*)sW)[t] = ((const h16x8*)W2p)[t];
    for (int t = threadIdx.x; t < 544; t += 256) sw1[t] = w1c[t];
    __syncthreads();

    int lane = threadIdx.x & 63;
    int wid = threadIdx.x >> 6;
    int ebase = blockIdx.x * 128 + wid * 32;
    int rr = lane & 15;
    int e0 = ebase + rr;
    int e1 = ebase + 16 + rr;
    int di0 = dstS[e0], si0 = srcS[e0];
    int di1 = dstS[e1], si1 = srcS[e1];
    _Float16 n20 = (_Float16)n2S[e0];
    _Float16 n21 = (_Float16)n2S[e1];
    const int ak = (lane >> 4) * 8;
    const _Float16* pa0 = TA + (size_t)di0 * 544 + ak;
    const _Float16* pb0 = TB + (size_t)si0 * 544 + ak;
    const _Float16* pa1 = TA + (size_t)di1 * 544 + ak;
    const _Float16* pb1 = TB + (size_t)si1 * 544 + ak;

    const _Float16 nl2e = (_Float16)(-1.44269504f);
    f32x4 acc0 = {0.f, 0.f, 0.f, 0.f};
    f32x4 acc1 = {0.f, 0.f, 0.f, 0.f};

    h16x8 bufA[16], bufB[16], bufT[4];

    auto issue4 = [&](h16x8* buf, int K) {
#pragma unroll
        for (int q = 0; q < 4; ++q) {
            buf[q * 4 + 0] = *(const h16x8*)(pa0 + (K + q) * 32);
            buf[q * 4 + 1] = *(const h16x8*)(pb0 + (K + q) * 32);
            buf[q * 4 + 2] = *(const h16x8*)(pa1 + (K + q) * 32);
            buf[q * 4 + 3] = *(const h16x8*)(pb1 + (K + q) * 32);
        }
    };
    auto step = [&](const h16x8* buf, int q, int ks) {
        h16x8 va0 = buf[q * 4 + 0], vb0 = buf[q * 4 + 1];
        h16x8 va1 = buf[q * 4 + 2], vb1 = buf[q * 4 + 3];
        h16x8 wv = *(const h16x8*)(sw1 + ks * 32 + ak);
        h16x8 x0 = va0 + vb0 + wv * n20;
        h16x8 ev0 = __builtin_elementwise_exp2(x0 * nl2e);
        h16x8 d0 = ev0 + (_Float16)1.0f;
        h16x8 r0;
#pragma unroll
        for (int j = 0; j < 8; ++j) r0[j] = __builtin_amdgcn_rcph(d0[j]);
        h16x8 m0 = x0 * r0;
        h16x8 x1 = va1 + vb1 + wv * n21;
        h16x8 ev1 = __builtin_elementwise_exp2(x1 * nl2e);
        h16x8 d1 = ev1 + (_Float16)1.0f;
        h16x8 r1;
#pragma unroll
        for (int j = 0; j < 8; ++j) r1[j] = __builtin_amdgcn_rcph(d1[j]);
        h16x8 m1 = x1 * r1;
        h16x8 bh = *(const h16x8*)(sW + (ks * 64 + lane) * 8);
        acc0 = __builtin_amdgcn_mfma_f32_16x16x32_f16(m0, bh, acc0, 0, 0, 0);
        acc1 = __builtin_amdgcn_mfma_f32_16x16x32_f16(m1, bh, acc1, 0, 0, 0);
    };

    issue4(bufA, 0);
    __builtin_amdgcn_sched_barrier(0);
    issue4(bufB, 4);
    __builtin_amdgcn_sched_barrier(0);
#pragma unroll
    for (int q = 0; q < 4; ++q) step(bufA, q, q);
    issue4(bufA, 8);
    __builtin_amdgcn_sched_barrier(0);
#pragma unroll
    for (int q = 0; q < 4; ++q) step(bufB, q, 4 + q);
    issue4(bufB, 12);
    __builtin_amdgcn_sched_barrier(0);
#pragma unroll
    for (int q = 0; q < 4; ++q) step(bufA, q, 8 + q);
    bufT[0] = *(const h16x8*)(pa0 + 16 * 32);
    bufT[1] = *(const h16x8*)(pb0 + 16 * 32);
    bufT[2] = *(const h16x8*)(pa1 + 16 * 32);
    bufT[3] = *(const h16x8*)(pb1 + 16 * 32);
    __builtin_amdgcn_sched_barrier(0);
#pragma unroll
    for (int q = 0; q < 4; ++q) step(bufB, q, 12 + q);
    step(bufT, 0, 16);

    int col = lane & 15;
    float b2 = bm2l[col];
#pragma unroll
    for (int i = 0; i < 4; ++i) {
        int ea = ebase + (lane >> 4) * 4 + i;
        float v0 = swish_fast(acc0[i] + b2);
        unsafeAtomicAdd(&agg[(size_t)dstS[ea] * 16 + col], v0);
        int eb = ea + 16;
        float v1 = swish_fast(acc1[i] + b2);
        unsafeAtomicAdd(&agg[(size_t)dstS[eb] * 16 + col], v1);
    }
}

// ---------------- readout ----------------
__global__ void readout(const float* __restrict__ pooled, const float* __restrict__ Wr1,
                        const float* __restrict__ br1, const float* __restrict__ Wr2,
                        const float* __restrict__ br2, float* __restrict__ out) {
    __shared__ float row[128];
    __shared__ float tt[128];
    int g = blockIdx.x;
    int t = threadIdx.x;
    row[t] = pooled[g * 128 + t];
    __syncthreads();
    float s = br1[t];
    for (int k = 0; k < 128; ++k) s += row[k] * Wr1[k * 128 + t];
    tt[t] = swish_fast(s);
    __syncthreads();
    if (t < 12) {
        float o = br2[t];
        for (int j = 0; j < 128; ++j) o += tt[j] * Wr2[j * 12 + t];
        out[g * 12 + t] = o;
    }
}

extern "C" void kernel_launch(void* const* d_in, const int* in_sizes, int n_in,
                              void* d_out, int out_size, void* d_ws, size_t ws_size,
                              hipStream_t stream) {
    const float* pos = (const float*)d_in[0];
    const int* z = (const int*)d_in[1];
    const int* ei = (const int*)d_in[2];
    const int* batch = (const int*)d_in[3];
    const float* emb = (const float*)d_in[4];
    const float* Wm1 = (const float*)d_in[5];
    const float* bm1 = (const float*)d_in[6];
    const float* Wm2 = (const float*)d_in[7];
    const float* bm2 = (const float*)d_in[8];
    const float* Wu1 = (const float*)d_in[9];
    const float* bu1 = (const float*)d_in[10];
    const float* Wu2 = (const float*)d_in[11];
    const float* bu2 = (const float*)d_in[12];
    const float* Wp1 = (const float*)d_in[13];
    const float* bp1v = (const float*)d_in[14];
    const float* Wp2 = (const float*)d_in[15];
    const float* bp2v = (const float*)d_in[16];
    const float* Wr1 = (const float*)d_in[17];
    const float* br1 = (const float*)d_in[18];
    const float* Wr2 = (const float*)d_in[19];
    const float* br2 = (const float*)d_in[20];

    const int N = in_sizes[0] / 3;   // 50000
    const int E = in_sizes[2] / 2;   // 800000
    const int G = out_size / 12;     // 1000
    const int* src = ei;
    const int* dstp = ei + E;
    const int stripeSz = (N + NSTRIPE - 1) / NSTRIPE;
    const int KN = NSTRIPE * N;
    const int NB = (KN + 255) / 256;

    char* ws = (char*)d_ws;
    size_t off = 0;
    auto alloc = [&](size_t bytes) -> char* {
        char* p = ws + off;
        off += (bytes + 255) & ~(size_t)255;
        return p;
    };
    _Float16* TA = (_Float16*)alloc((size_t)N * 544 * 2);
    _Float16* TB = (_Float16*)alloc((size_t)N * 544 * 2);
    float* hf = (float*)alloc((size_t)N * 128 * 4);
    _Float16* hhi = (_Float16*)alloc((size_t)N * 128 * 2);
    float* agg = (float*)alloc((size_t)N * 16 * 4);
    float* pooled = (float*)alloc((size_t)G * 128 * 4);
    int* hist = (int*)alloc((size_t)KN * 4);
    int* cursor = (int*)alloc((size_t)KN * 4);
    int* blocksum = (int*)alloc((size_t)NB * 4);
    int* perm = (int*)alloc((size_t)E * 4);
    int* srcS = (int*)alloc((size_t)E * 4);
    int* dstS = (int*)alloc((size_t)E * 4);
    float* n2S = (float*)alloc((size_t)E * 4);
    _Float16* Bp1A = (_Float16*)alloc((size_t)7 * 139264 * 2);
    float* biasA = (float*)alloc((size_t)7 * 1088 * 4);
    _Float16* w1cA = (_Float16*)alloc((size_t)7 * 544 * 2);
    _Float16* W2pA = (_Float16*)alloc((size_t)7 * 8704 * 2);
    _Float16* BpU1A = (_Float16*)alloc((size_t)7 * 40960 * 2);
    _Float16* BpU2A = (_Float16*)alloc((size_t)7 * 32768 * 2);
    _Float16* BpP1 = (_Float16*)alloc(16384 * 2);
    _Float16* BpP2 = (_Float16*)alloc(16384 * 2);

    init_nodes<<<(N * 128) / 256, 256, 0, stream>>>(z, emb, hf, hhi, N);

    // one-time: counting sort of edges by (dst_stripe, src)
    hipMemsetAsync(hist, 0, (size_t)KN * 4, stream);
    hist_kernel<<<(E + 255) / 256, 256, 0, stream>>>(src, dstp, hist, E, N, stripeSz);
    scan_p1<<<NB, 256, 0, stream>>>(hist, blocksum, KN);
    scan_p2<<<1, 1024, 0, stream>>>(blocksum, NB);
    scan_p3<<<NB, 256, 0, stream>>>(hist, blocksum, cursor, KN);
    scatter_kernel<<<(E + 255) / 256, 256, 0, stream>>>(src, dstp, cursor, perm, E, N, stripeSz);
    reorder_kernel<<<(E + 255) / 256, 256, 0, stream>>>(perm, src, dstp, pos, srcS, dstS, n2S, E);

    // one-time: pack all layers' weights
    pack_msg1<<<dim3(139264 / 256, 7), 256, 0, stream>>>(Wm1, bm1, Wm2, Bp1A, biasA, w1cA, W2pA);
    pack_generic<<<dim3(160, 7), 256, 0, stream>>>(Wu1, (size_t)144 * 256, 144, 256, BpU1A, 40960);
    pack_generic<<<dim3(128, 7), 256, 0, stream>>>(Wu2, (size_t)256 * 128, 256, 128, BpU2A, 32768);
    pack_generic<<<dim3(64, 1), 256, 0, stream>>>(Wp1, 0, 128, 128, BpP1, 0);
    pack_generic<<<dim3(64, 1), 256, 0, stream>>>(Wp2, 0, 128, 128, BpP2, 0);
    hipMemsetAsync(pooled, 0, (size_t)G * 128 * 4, stream);

    const int gA = (N + 63) / 64;
    tab_gemm<<<gA, 256, 0, stream>>>(hhi, Bp1A, biasA, TA, TB, agg, N);
    for (int l = 0; l < 7; ++l) {
        edge_kernel<<<E / 128, 256, 0, stream>>>(TA, TB, w1cA + (size_t)l * 544,
                                                 W2pA + (size_t)l * 8704, bm2 + l * 16,
                                                 srcS, dstS, n2S, agg);
        if (l < 6) {
            up_tab<0><<<gA, 256, 0, stream>>>(
                agg, hf, BpU1A + (size_t)l * 40960, bu1 + l * 256,
                BpU2A + (size_t)l * 32768, bu2 + l * 128,
                Bp1A + (size_t)(l + 1) * 139264, biasA + (size_t)(l + 1) * 1088,
                nullptr, nullptr, TA, TB, nullptr, nullptr, N);
        } else {
            up_tab<1><<<gA, 256, 0, stream>>>(
                agg, hf, BpU1A + (size_t)l * 40960, bu1 + l * 256,
                BpU2A + (size_t)l * 32768, bu2 + l * 128,
                BpP1, bp1v, BpP2, bp2v,
                nullptr, nullptr, batch, pooled, N);
        }
    }
    readout<<<G, 128, 0, stream>>>(pooled, Wr1, br1, Wr2, br2, (float*)d_out);
}